// Round 1
// baseline (3030.431 us; speedup 1.0000x reference)
//
#include <hip/hip_runtime.h>
#include <hip/hip_bf16.h>
#include <math.h>

// CrossCBR: two L=2 graph propagations + bundle agg + BPR/InfoNCE losses.
// NU=50000, NBU=20000, NI=100000, D=64, L=2, C_TEMP=0.25
static constexpr int NUc  = 50000;
static constexpr int NBUc = 20000;
static constexpr int NIc  = 100000;
static constexpr int NILc = NUc + NIc;   // 150000 nodes in user-item graph
static constexpr int NBLc = NUc + NBUc;  // 70000 nodes in user-bundle graph

__device__ __forceinline__ float wredsum(float v) {
  #pragma unroll
  for (int m = 32; m >= 1; m >>= 1) v += __shfl_xor(v, m, 64);
  return v;
}

// degree of symmetric graph: deg[u] += 1, deg[x+off] += 1 per undirected edge
__global__ void k_deg_sym(const int* __restrict__ eu, const int* __restrict__ ex,
                          int E, int off, float* __restrict__ deg) {
  int e = blockIdx.x * blockDim.x + threadIdx.x;
  if (e >= E) return;
  unsafeAtomicAdd(&deg[eu[e]], 1.0f);
  unsafeAtomicAdd(&deg[ex[e] + off], 1.0f);
}

__global__ void k_dinv(float* __restrict__ deg, int n) {
  int i = blockIdx.x * blockDim.x + threadIdx.x;
  if (i >= n) return;
  deg[i] = 1.0f / (sqrtf(deg[i]) + 1e-8f);
}

// symmetric spmm: out[u] += v*f[x]; out[x] += v*f[u]; v = dinv[u]*dinv[x]*scale
// source features split in two segments: rows [0,off) -> fA, rows [off,n) -> fB
__global__ void k_spmm_sym(const int* __restrict__ eu, const int* __restrict__ ex,
                           int E, int off, const float* __restrict__ dinv,
                           const float* __restrict__ fA, const float* __restrict__ fB,
                           float* __restrict__ out, float scale) {
  long idx = (long)blockIdx.x * blockDim.x + threadIdx.x;
  if (idx >= (long)E * 64) return;
  int e = (int)(idx >> 6);
  int d = (int)(idx & 63);
  int u = eu[e];            // always < off (user side)
  int x = ex[e] + off;      // >= off
  float v = dinv[u] * dinv[x] * scale;
  float a = fA[(long)u * 64 + d];
  float b = fB[(long)(x - off) * 64 + d];
  unsafeAtomicAdd(&out[(long)u * 64 + d], v * b);
  unsafeAtomicAdd(&out[(long)x * 64 + d], v * a);
}

// inv[row] = 1 / max(||f[row]||, 1e-12), one 64-lane wave per row
__global__ void k_rownorm_inv(const float* __restrict__ f, float* __restrict__ inv, int n) {
  int row = blockIdx.x * (blockDim.x >> 6) + (threadIdx.x >> 6);
  int lane = threadIdx.x & 63;
  if (row >= n) return;
  float v = f[(long)row * 64 + lane];
  float s = wredsum(v * v);
  if (lane == 0) inv[row] = 1.0f / fmaxf(sqrtf(s), 1e-12f);
}

// acc = f0 + F1/||F1|| + F2/||F2|| ; f0 split in two segments
__global__ void k_acc(const float* __restrict__ fA, const float* __restrict__ fB, int off, int n,
                      const float* __restrict__ F1, const float* __restrict__ inv1,
                      const float* __restrict__ F2, const float* __restrict__ inv2,
                      float* __restrict__ acc) {
  long idx = (long)blockIdx.x * blockDim.x + threadIdx.x;
  if (idx >= (long)n * 64) return;
  int r = (int)(idx >> 6);
  float base = (r < off) ? fA[idx] : fB[idx - (long)off * 64];
  acc[idx] = base + F1[idx] * inv1[r] + F2[idx] * inv2[r];
}

__global__ void k_deg1(const int* __restrict__ b, int E, float* __restrict__ deg) {
  int e = blockIdx.x * blockDim.x + threadIdx.x;
  if (e >= E) return;
  unsafeAtomicAdd(&deg[b[e]], 1.0f);
}

// IL_bundles[b] += (1/(deg[b]+1e-8)) * acc_items[i]
__global__ void k_bundle_agg(const int* __restrict__ bb, const int* __restrict__ bi, int E,
                             const float* __restrict__ deg, const float* __restrict__ items,
                             float* __restrict__ out) {
  long idx = (long)blockIdx.x * blockDim.x + threadIdx.x;
  if (idx >= (long)E * 64) return;
  int e = (int)(idx >> 6);
  int d = (int)(idx & 63);
  int b = bb[e];
  int i = bi[e];
  float w = 1.0f / (deg[b] + 1e-8f);
  unsafeAtomicAdd(&out[(long)b * 64 + d], w * items[(long)i * 64 + d]);
}

__global__ void k_gather(const int* __restrict__ idx, int nrow, const float* __restrict__ src,
                         int srcOff, float* __restrict__ dst) {
  long i = (long)blockIdx.x * blockDim.x + threadIdx.x;
  if (i >= (long)nrow * 64) return;
  int r = (int)(i >> 6);
  int d = (int)(i & 63);
  dst[i] = src[(long)(idx[r] + srcOff) * 64 + d];
}

// dst[row] = src_row / max(||src_row||,1e-12); src has row stride `stride` floats
__global__ void k_normalize(const float* __restrict__ src, int stride, float* __restrict__ dst, int n) {
  int row = blockIdx.x * (blockDim.x >> 6) + (threadIdx.x >> 6);
  int lane = threadIdx.x & 63;
  if (row >= n) return;
  float v = src[(long)row * stride + lane];
  float s = wredsum(v * v);
  float inv = 1.0f / fmaxf(sqrtf(s), 1e-12f);
  dst[(long)row * 64 + lane] = v * inv;
}

// bpr_loss accumulation: -mean(log_sigmoid(pred0 - pred1))
__global__ void k_bpr(const float* __restrict__ ILu, const float* __restrict__ ILb2,
                      const float* __restrict__ BLu, const float* __restrict__ BLb2,
                      int B, float* __restrict__ out) {
  int row = blockIdx.x * (blockDim.x >> 6) + (threadIdx.x >> 6);
  int lane = threadIdx.x & 63;
  if (row >= B) return;
  float t = ILu[(long)row * 64 + lane] *
              (ILb2[(long)(2 * row) * 64 + lane] - ILb2[(long)(2 * row + 1) * 64 + lane]) +
            BLu[(long)row * 64 + lane] *
              (BLb2[(long)(2 * row) * 64 + lane] - BLb2[(long)(2 * row + 1) * 64 + lane]);
  float x = wredsum(t);
  if (lane == 0) {
    // log_sigmoid(x) = -(max(-x,0) + log1p(exp(-|x|)))
    float ls = -(fmaxf(-x, 0.0f) + log1pf(expf(-fabsf(x))));
    unsafeAtomicAdd(&out[0], -ls / (float)B);
  }
}

// InfoNCE: per-row r, x_c = dot(P[r],A[c])/temp ; adds -(x_r - logsumexp_c x_c)*coeffOverB
__global__ void k_closs(const float* __restrict__ P, const float* __restrict__ A, int B,
                        float coeffOverB, float* __restrict__ out) {
  __shared__ float Psh[64];
  __shared__ float sm[256];
  __shared__ float ss[256];
  __shared__ float sdiag;
  int r = blockIdx.x;
  int t = threadIdx.x;
  if (t < 64) Psh[t] = P[(long)r * 64 + t];
  __syncthreads();
  float m = -1e30f, s = 0.0f;
  for (int c = t; c < B; c += 256) {
    const float4* a4 = (const float4*)(A + (long)c * 64);
    float dot = 0.0f;
    #pragma unroll
    for (int q = 0; q < 16; q++) {
      float4 av = a4[q];
      dot += Psh[4 * q] * av.x + Psh[4 * q + 1] * av.y + Psh[4 * q + 2] * av.z + Psh[4 * q + 3] * av.w;
    }
    float x = dot * 4.0f;  // 1/C_TEMP
    if (c == r) sdiag = x;
    if (x > m) { s = s * expf(m - x) + 1.0f; m = x; }
    else       { s += expf(x - m); }
  }
  sm[t] = m; ss[t] = s;
  __syncthreads();
  for (int w = 128; w >= 1; w >>= 1) {
    if (t < w) {
      float m2 = sm[t + w], s2 = ss[t + w];
      float M = fmaxf(sm[t], m2);
      ss[t] = ss[t] * expf(sm[t] - M) + s2 * expf(m2 - M);
      sm[t] = M;
    }
    __syncthreads();
  }
  if (t == 0) {
    float lse = sm[0] + logf(ss[0]);
    unsafeAtomicAdd(&out[1], -(sdiag - lse) * coeffOverB);
  }
}

extern "C" void kernel_launch(void* const* d_in, const int* in_sizes, int n_in,
                              void* d_out, int out_size, void* d_ws, size_t ws_size,
                              hipStream_t stream) {
  const int* users   = (const int*)d_in[0];
  const int* bundles = (const int*)d_in[1];
  const int* ui_u    = (const int*)d_in[2];
  const int* ui_i    = (const int*)d_in[3];
  const int* ub_u    = (const int*)d_in[4];
  const int* ub_b    = (const int*)d_in[5];
  const int* bi_b    = (const int*)d_in[6];
  const int* bi_i    = (const int*)d_in[7];
  const float* userF = (const float*)d_in[8];
  const float* bundF = (const float*)d_in[9];
  const float* itemF = (const float*)d_in[10];
  float* out = (float*)d_out;

  const int B    = in_sizes[0];
  const int E_ui = in_sizes[2];
  const int E_ub = in_sizes[4];
  const int E_bi = in_sizes[6];

  float* ws = (float*)d_ws;
  size_t off = 0;
  auto alloc = [&](size_t nfloat) -> float* {
    float* p = ws + off;
    off += (nfloat + 63) & ~(size_t)63;
    return p;
  };
  float* F1   = alloc((size_t)NILc * 64);   // layer-1 output (reused for BL)
  float* F2   = alloc((size_t)NILc * 64);   // layer-2 output
  float* ACC  = alloc((size_t)NILc * 64);   // materialized acc
  float* DINV = alloc(NILc);                // deg -> dinv
  float* INV1 = alloc(NILc);
  float* INV2 = alloc(NILc);
  float* DEGB = alloc(NBUc);
  float* ILB  = alloc((size_t)NBUc * 64);   // IL_bundles (persists past BL phase)
  float* ILu  = alloc((size_t)B * 64);
  float* BLu  = alloc((size_t)B * 64);
  float* ILb2 = alloc((size_t)B * 128);
  float* BLb2 = alloc((size_t)B * 128);
  float* PN   = alloc((size_t)B * 64);
  float* AN   = alloc((size_t)B * 64);
  (void)ws_size; (void)n_in; (void)out_size;

  const int T = 256;
  auto nb = [&](long total) { return (int)((total + T - 1) / T); };

  // ---------------- IL propagate: users+items graph ----------------
  hipMemsetAsync(DINV, 0, sizeof(float) * NILc, stream);
  k_deg_sym<<<nb(E_ui), T, 0, stream>>>(ui_u, ui_i, E_ui, NUc, DINV);
  k_dinv<<<nb(NILc), T, 0, stream>>>(DINV, NILc);
  hipMemsetAsync(F1, 0, sizeof(float) * (size_t)NILc * 64, stream);
  k_spmm_sym<<<nb((long)E_ui * 64), T, 0, stream>>>(ui_u, ui_i, E_ui, NUc, DINV,
                                                    userF, itemF, F1, 0.5f);
  k_rownorm_inv<<<(NILc + 3) / 4, T, 0, stream>>>(F1, INV1, NILc);
  hipMemsetAsync(F2, 0, sizeof(float) * (size_t)NILc * 64, stream);
  k_spmm_sym<<<nb((long)E_ui * 64), T, 0, stream>>>(ui_u, ui_i, E_ui, NUc, DINV,
                                                    F1, F1 + (size_t)NUc * 64, F2, 1.0f / 3.0f);
  k_rownorm_inv<<<(NILc + 3) / 4, T, 0, stream>>>(F2, INV2, NILc);
  k_acc<<<nb((long)NILc * 64), T, 0, stream>>>(userF, itemF, NUc, NILc, F1, INV1, F2, INV2, ACC);
  k_gather<<<nb((long)B * 64), T, 0, stream>>>(users, B, ACC, 0, ILu);

  // bundle aggregation from IL item embeddings
  hipMemsetAsync(DEGB, 0, sizeof(float) * NBUc, stream);
  hipMemsetAsync(ILB, 0, sizeof(float) * (size_t)NBUc * 64, stream);
  k_deg1<<<nb(E_bi), T, 0, stream>>>(bi_b, E_bi, DEGB);
  k_bundle_agg<<<nb((long)E_bi * 64), T, 0, stream>>>(bi_b, bi_i, E_bi, DEGB,
                                                      ACC + (size_t)NUc * 64, ILB);
  k_gather<<<nb((long)2 * B * 64), T, 0, stream>>>(bundles, 2 * B, ILB, 0, ILb2);

  // ---------------- BL propagate: users+bundles graph (reuse buffers) ----------------
  hipMemsetAsync(DINV, 0, sizeof(float) * NBLc, stream);
  k_deg_sym<<<nb(E_ub), T, 0, stream>>>(ub_u, ub_b, E_ub, NUc, DINV);
  k_dinv<<<nb(NBLc), T, 0, stream>>>(DINV, NBLc);
  hipMemsetAsync(F1, 0, sizeof(float) * (size_t)NBLc * 64, stream);
  k_spmm_sym<<<nb((long)E_ub * 64), T, 0, stream>>>(ub_u, ub_b, E_ub, NUc, DINV,
                                                    userF, bundF, F1, 0.5f);
  k_rownorm_inv<<<(NBLc + 3) / 4, T, 0, stream>>>(F1, INV1, NBLc);
  hipMemsetAsync(F2, 0, sizeof(float) * (size_t)NBLc * 64, stream);
  k_spmm_sym<<<nb((long)E_ub * 64), T, 0, stream>>>(ub_u, ub_b, E_ub, NUc, DINV,
                                                    F1, F1 + (size_t)NUc * 64, F2, 1.0f / 3.0f);
  k_rownorm_inv<<<(NBLc + 3) / 4, T, 0, stream>>>(F2, INV2, NBLc);
  k_acc<<<nb((long)NBLc * 64), T, 0, stream>>>(userF, bundF, NUc, NBLc, F1, INV1, F2, INV2, ACC);
  k_gather<<<nb((long)B * 64), T, 0, stream>>>(users, B, ACC, 0, BLu);
  k_gather<<<nb((long)2 * B * 64), T, 0, stream>>>(bundles, 2 * B, ACC, NUc, BLb2);

  // ---------------- losses ----------------
  hipMemsetAsync(out, 0, 2 * sizeof(float), stream);
  k_bpr<<<(B + 3) / 4, T, 0, stream>>>(ILu, ILb2, BLu, BLb2, B, out);

  // c_loss part 1: normalized IL_u vs BL_u
  k_normalize<<<(B + 3) / 4, T, 0, stream>>>(ILu, 64, PN, B);
  k_normalize<<<(B + 3) / 4, T, 0, stream>>>(BLu, 64, AN, B);
  k_closs<<<B, 256, 0, stream>>>(PN, AN, B, 0.5f / (float)B, out);

  // c_loss part 2: normalized IL_b[:,0] vs BL_b[:,0] (stride 128 = row 0 of pairs)
  k_normalize<<<(B + 3) / 4, T, 0, stream>>>(ILb2, 128, PN, B);
  k_normalize<<<(B + 3) / 4, T, 0, stream>>>(BLb2, 128, AN, B);
  k_closs<<<B, 256, 0, stream>>>(PN, AN, B, 0.5f / (float)B, out);
}

// Round 3
// 1698.573 us; speedup vs baseline: 1.7841x; 1.7841x over previous
//
#include <hip/hip_runtime.h>
#include <hip/hip_bf16.h>
#include <math.h>

// CrossCBR: two L=2 graph propagations + bundle agg + BPR/InfoNCE losses.
// R2 (resubmit after infra failure): CSR-gather SpMM (no float atomics).
// Build CSR per graph on device, then one wave per output row, register
// accumulate, single coalesced store.
static constexpr int NUc  = 50000;
static constexpr int NBUc = 20000;
static constexpr int NIc  = 100000;
static constexpr int NILc = NUc + NIc;   // 150000 nodes in user-item graph
static constexpr int NBLc = NUc + NBUc;  // 70000 nodes in user-bundle graph

__device__ __forceinline__ float wredsum(float v) {
  #pragma unroll
  for (int m = 32; m >= 1; m >>= 1) v += __shfl_xor(v, m, 64);
  return v;
}

// ---------------- CSR build ----------------
__global__ void k_count_sym(const int* __restrict__ eu, const int* __restrict__ ex,
                            int E, int off, int* __restrict__ cnt) {
  int e = blockIdx.x * blockDim.x + threadIdx.x;
  if (e >= E) return;
  atomicAdd(&cnt[eu[e]], 1);
  atomicAdd(&cnt[ex[e] + off], 1);
}

__global__ void k_count1(const int* __restrict__ er, int E, int* __restrict__ cnt) {
  int e = blockIdx.x * blockDim.x + threadIdx.x;
  if (e >= E) return;
  atomicAdd(&cnt[er[e]], 1);
}

// hierarchical exclusive scan: block of 256 covers 1024 elements
__global__ void k_scan_block(const int* __restrict__ in, int n, int* __restrict__ out,
                             int* __restrict__ bsum) {
  __shared__ int sh[256];
  int t = threadIdx.x;
  long base = (long)blockIdx.x * 1024 + (long)t * 4;
  int v0 = (base     < n) ? in[base]     : 0;
  int v1 = (base + 1 < n) ? in[base + 1] : 0;
  int v2 = (base + 2 < n) ? in[base + 2] : 0;
  int v3 = (base + 3 < n) ? in[base + 3] : 0;
  int tsum = v0 + v1 + v2 + v3;
  sh[t] = tsum;
  __syncthreads();
  for (int o = 1; o < 256; o <<= 1) {
    int x = (t >= o) ? sh[t - o] : 0;
    __syncthreads();
    sh[t] += x;
    __syncthreads();
  }
  int excl = sh[t] - tsum;
  if (t == 255) bsum[blockIdx.x] = sh[255];
  if (base     < n) out[base]     = excl;
  if (base + 1 < n) out[base + 1] = excl + v0;
  if (base + 2 < n) out[base + 2] = excl + v0 + v1;
  if (base + 3 < n) out[base + 3] = excl + v0 + v1 + v2;
}

__global__ void k_scan_bsum(int* __restrict__ bsum, int nb) {  // nb <= 256
  __shared__ int sh[256];
  int t = threadIdx.x;
  int v = (t < nb) ? bsum[t] : 0;
  sh[t] = v;
  __syncthreads();
  for (int o = 1; o < 256; o <<= 1) {
    int x = (t >= o) ? sh[t - o] : 0;
    __syncthreads();
    sh[t] += x;
    __syncthreads();
  }
  if (t < nb) bsum[t] = sh[t] - v;
}

__global__ void k_scan_add(int* __restrict__ out, int n, const int* __restrict__ bsum) {
  long i = (long)blockIdx.x * blockDim.x + threadIdx.x;
  if (i < n) out[i] += bsum[i >> 10];
}

__global__ void k_copy_i(const int* __restrict__ src, int* __restrict__ dst, int n) {
  int i = blockIdx.x * blockDim.x + threadIdx.x;
  if (i < n) dst[i] = src[i];
}

__global__ void k_scatter_sym(const int* __restrict__ eu, const int* __restrict__ ex,
                              int E, int off, int* __restrict__ cur, int* __restrict__ colv) {
  int e = blockIdx.x * blockDim.x + threadIdx.x;
  if (e >= E) return;
  int u = eu[e], x = ex[e] + off;
  int p1 = atomicAdd(&cur[u], 1); colv[p1] = x;
  int p2 = atomicAdd(&cur[x], 1); colv[p2] = u;
}

__global__ void k_scatter1(const int* __restrict__ er, const int* __restrict__ ec,
                           int E, int* __restrict__ cur, int* __restrict__ colv) {
  int e = blockIdx.x * blockDim.x + threadIdx.x;
  if (e >= E) return;
  int p = atomicAdd(&cur[er[e]], 1);
  colv[p] = ec[e];
}

__global__ void k_dinv_rp(const int* __restrict__ rp, float* __restrict__ dinv, int n) {
  int i = blockIdx.x * blockDim.x + threadIdx.x;
  if (i >= n) return;
  float d = (float)(rp[i + 1] - rp[i]);
  dinv[i] = 1.0f / (sqrtf(d) + 1e-8f);
}

// ---------------- gather SpMM ----------------
// out[row] = dinv[row]*scale * sum_e dinv[col_e] * f[col_e]; f split at `off` into fA/fB
__global__ void k_spmm_csr(const int* __restrict__ rp, const int* __restrict__ col,
                           const float* __restrict__ dinv,
                           const float* __restrict__ fA, const float* __restrict__ fB,
                           int off, float* __restrict__ out, float scale, int n) {
  int row = blockIdx.x * (blockDim.x >> 6) + (threadIdx.x >> 6);
  int lane = threadIdx.x & 63;
  if (row >= n) return;
  int s = rp[row], e = rp[row + 1];
  float acc = 0.0f;
  for (int chunk = s; chunk < e; chunk += 64) {
    int nc = min(64, e - chunk);
    int ci = 0; float dv = 0.0f;
    if (lane < nc) { ci = col[chunk + lane]; dv = dinv[ci]; }
    int j = 0;
    for (; j + 2 <= nc; j += 2) {
      int c0 = __shfl(ci, j, 64);     float v0 = __shfl(dv, j, 64);
      int c1 = __shfl(ci, j + 1, 64); float v1 = __shfl(dv, j + 1, 64);
      const float* s0 = (c0 < off) ? fA + (long)c0 * 64 : fB + ((long)c0 - off) * 64;
      const float* s1 = (c1 < off) ? fA + (long)c1 * 64 : fB + ((long)c1 - off) * 64;
      float x0 = s0[lane];
      float x1 = s1[lane];
      acc = fmaf(v0, x0, acc);
      acc = fmaf(v1, x1, acc);
    }
    if (j < nc) {
      int c0 = __shfl(ci, j, 64); float v0 = __shfl(dv, j, 64);
      const float* s0 = (c0 < off) ? fA + (long)c0 * 64 : fB + ((long)c0 - off) * 64;
      acc = fmaf(v0, s0[lane], acc);
    }
  }
  out[(long)row * 64 + lane] = acc * (dinv[row] * scale);
}

// bundle mean-agg via CSR: out[row] = (1/(deg+1e-8)) * sum items[col]
__global__ void k_agg_csr(const int* __restrict__ rp, const int* __restrict__ col,
                          const float* __restrict__ src, float* __restrict__ out, int n) {
  int row = blockIdx.x * (blockDim.x >> 6) + (threadIdx.x >> 6);
  int lane = threadIdx.x & 63;
  if (row >= n) return;
  int s = rp[row], e = rp[row + 1];
  float acc = 0.0f;
  for (int chunk = s; chunk < e; chunk += 64) {
    int nc = min(64, e - chunk);
    int ci = 0;
    if (lane < nc) ci = col[chunk + lane];
    for (int j = 0; j < nc; j++) {
      int c0 = __shfl(ci, j, 64);
      acc += src[(long)c0 * 64 + lane];
    }
  }
  float w = 1.0f / ((float)(e - s) + 1e-8f);
  out[(long)row * 64 + lane] = acc * w;
}

// ---------------- misc ----------------
__global__ void k_rownorm_inv(const float* __restrict__ f, float* __restrict__ inv, int n) {
  int row = blockIdx.x * (blockDim.x >> 6) + (threadIdx.x >> 6);
  int lane = threadIdx.x & 63;
  if (row >= n) return;
  float v = f[(long)row * 64 + lane];
  float s = wredsum(v * v);
  if (lane == 0) inv[row] = 1.0f / fmaxf(sqrtf(s), 1e-12f);
}

__global__ void k_acc(const float* __restrict__ fA, const float* __restrict__ fB, int off, int n,
                      const float* __restrict__ F1, const float* __restrict__ inv1,
                      const float* __restrict__ F2, const float* __restrict__ inv2,
                      float* __restrict__ acc) {
  long idx = (long)blockIdx.x * blockDim.x + threadIdx.x;
  if (idx >= (long)n * 64) return;
  int r = (int)(idx >> 6);
  float base = (r < off) ? fA[idx] : fB[idx - (long)off * 64];
  acc[idx] = base + F1[idx] * inv1[r] + F2[idx] * inv2[r];
}

__global__ void k_gather(const int* __restrict__ idx, int nrow, const float* __restrict__ src,
                         int srcOff, float* __restrict__ dst) {
  long i = (long)blockIdx.x * blockDim.x + threadIdx.x;
  if (i >= (long)nrow * 64) return;
  int r = (int)(i >> 6);
  int d = (int)(i & 63);
  dst[i] = src[(long)(idx[r] + srcOff) * 64 + d];
}

__global__ void k_normalize(const float* __restrict__ src, int stride, float* __restrict__ dst, int n) {
  int row = blockIdx.x * (blockDim.x >> 6) + (threadIdx.x >> 6);
  int lane = threadIdx.x & 63;
  if (row >= n) return;
  float v = src[(long)row * stride + lane];
  float s = wredsum(v * v);
  float inv = 1.0f / fmaxf(sqrtf(s), 1e-12f);
  dst[(long)row * 64 + lane] = v * inv;
}

__global__ void k_bpr(const float* __restrict__ ILu, const float* __restrict__ ILb2,
                      const float* __restrict__ BLu, const float* __restrict__ BLb2,
                      int B, float* __restrict__ out) {
  int row = blockIdx.x * (blockDim.x >> 6) + (threadIdx.x >> 6);
  int lane = threadIdx.x & 63;
  if (row >= B) return;
  float t = ILu[(long)row * 64 + lane] *
              (ILb2[(long)(2 * row) * 64 + lane] - ILb2[(long)(2 * row + 1) * 64 + lane]) +
            BLu[(long)row * 64 + lane] *
              (BLb2[(long)(2 * row) * 64 + lane] - BLb2[(long)(2 * row + 1) * 64 + lane]);
  float x = wredsum(t);
  if (lane == 0) {
    float ls = -(fmaxf(-x, 0.0f) + log1pf(expf(-fabsf(x))));
    unsafeAtomicAdd(&out[0], -ls / (float)B);
  }
}

__global__ void k_closs(const float* __restrict__ P, const float* __restrict__ A, int B,
                        float coeffOverB, float* __restrict__ out) {
  __shared__ float Psh[64];
  __shared__ float sm[256];
  __shared__ float ss[256];
  __shared__ float sdiag;
  int r = blockIdx.x;
  int t = threadIdx.x;
  if (t < 64) Psh[t] = P[(long)r * 64 + t];
  __syncthreads();
  float m = -1e30f, s = 0.0f;
  for (int c = t; c < B; c += 256) {
    const float4* a4 = (const float4*)(A + (long)c * 64);
    float dot = 0.0f;
    #pragma unroll
    for (int q = 0; q < 16; q++) {
      float4 av = a4[q];
      dot += Psh[4 * q] * av.x + Psh[4 * q + 1] * av.y + Psh[4 * q + 2] * av.z + Psh[4 * q + 3] * av.w;
    }
    float x = dot * 4.0f;  // 1/C_TEMP
    if (c == r) sdiag = x;
    if (x > m) { s = s * expf(m - x) + 1.0f; m = x; }
    else       { s += expf(x - m); }
  }
  sm[t] = m; ss[t] = s;
  __syncthreads();
  for (int w = 128; w >= 1; w >>= 1) {
    if (t < w) {
      float m2 = sm[t + w], s2 = ss[t + w];
      float M = fmaxf(sm[t], m2);
      ss[t] = ss[t] * expf(sm[t] - M) + s2 * expf(m2 - M);
      sm[t] = M;
    }
    __syncthreads();
  }
  if (t == 0) {
    float lse = sm[0] + logf(ss[0]);
    unsafeAtomicAdd(&out[1], -(sdiag - lse) * coeffOverB);
  }
}

extern "C" void kernel_launch(void* const* d_in, const int* in_sizes, int n_in,
                              void* d_out, int out_size, void* d_ws, size_t ws_size,
                              hipStream_t stream) {
  const int* users   = (const int*)d_in[0];
  const int* bundles = (const int*)d_in[1];
  const int* ui_u    = (const int*)d_in[2];
  const int* ui_i    = (const int*)d_in[3];
  const int* ub_u    = (const int*)d_in[4];
  const int* ub_b    = (const int*)d_in[5];
  const int* bi_b    = (const int*)d_in[6];
  const int* bi_i    = (const int*)d_in[7];
  const float* userF = (const float*)d_in[8];
  const float* bundF = (const float*)d_in[9];
  const float* itemF = (const float*)d_in[10];
  float* out = (float*)d_out;

  const int B    = in_sizes[0];
  const int E_ui = in_sizes[2];
  const int E_ub = in_sizes[4];
  const int E_bi = in_sizes[6];

  float* ws = (float*)d_ws;
  size_t off = 0;
  auto alloc = [&](size_t nfloat) -> float* {
    float* p = ws + off;
    off += (nfloat + 63) & ~(size_t)63;
    return p;
  };
  float* F1   = alloc((size_t)NILc * 64);
  float* F2   = alloc((size_t)NILc * 64);
  float* ACC  = alloc((size_t)NILc * 64);
  float* DINV = alloc(NILc);
  float* INV1 = alloc(NILc);
  float* INV2 = alloc(NILc);
  float* ILB  = alloc((size_t)NBUc * 64);
  float* ILu  = alloc((size_t)B * 64);
  float* BLu  = alloc((size_t)B * 64);
  float* ILb2 = alloc((size_t)B * 128);
  float* BLb2 = alloc((size_t)B * 128);
  float* PN   = alloc((size_t)B * 64);
  float* AN   = alloc((size_t)B * 64);
  // CSR int buffers
  int* rp_ui  = (int*)alloc(NILc + 1);
  int* cur_ui = (int*)alloc(NILc + 1);
  int* col_ui = (int*)alloc(2 * (size_t)E_ui);
  int* rp_ub  = (int*)alloc(NBLc + 1);
  int* cur_ub = (int*)alloc(NBLc + 1);
  int* col_ub = (int*)alloc(2 * (size_t)E_ub);
  int* rp_bi  = (int*)alloc(NBUc + 1);
  int* cur_bi = (int*)alloc(NBUc + 1);
  int* col_bi = (int*)alloc((size_t)E_bi);
  int* bsum   = (int*)alloc(256);
  (void)ws_size; (void)n_in; (void)out_size;

  const int T = 256;
  auto nb = [&](long total) { return (int)((total + T - 1) / T); };

  auto scan_finish = [&](int* cnt, int* rp, int scan_n) {
    int nb1 = (scan_n + 1023) / 1024;
    k_scan_block<<<nb1, 256, 0, stream>>>(cnt, scan_n, rp, bsum);
    k_scan_bsum<<<1, 256, 0, stream>>>(bsum, nb1);
    k_scan_add<<<(scan_n + 255) / 256, 256, 0, stream>>>(rp, scan_n, bsum);
  };

  // ---- build CSR: UI (symmetric, 150K nodes, 2*E_ui directed edges) ----
  hipMemsetAsync(cur_ui, 0, sizeof(int) * (NILc + 1), stream);
  k_count_sym<<<nb(E_ui), T, 0, stream>>>(ui_u, ui_i, E_ui, NUc, cur_ui);
  scan_finish(cur_ui, rp_ui, NILc + 1);
  k_copy_i<<<nb(NILc), T, 0, stream>>>(rp_ui, cur_ui, NILc);
  k_scatter_sym<<<nb(E_ui), T, 0, stream>>>(ui_u, ui_i, E_ui, NUc, cur_ui, col_ui);

  // ---- build CSR: UB (symmetric, 70K nodes) ----
  hipMemsetAsync(cur_ub, 0, sizeof(int) * (NBLc + 1), stream);
  k_count_sym<<<nb(E_ub), T, 0, stream>>>(ub_u, ub_b, E_ub, NUc, cur_ub);
  scan_finish(cur_ub, rp_ub, NBLc + 1);
  k_copy_i<<<nb(NBLc), T, 0, stream>>>(rp_ub, cur_ub, NBLc);
  k_scatter_sym<<<nb(E_ub), T, 0, stream>>>(ub_u, ub_b, E_ub, NUc, cur_ub, col_ub);

  // ---- build CSR: BI (bundle->item, 20K rows) ----
  hipMemsetAsync(cur_bi, 0, sizeof(int) * (NBUc + 1), stream);
  k_count1<<<nb(E_bi), T, 0, stream>>>(bi_b, E_bi, cur_bi);
  scan_finish(cur_bi, rp_bi, NBUc + 1);
  k_copy_i<<<nb(NBUc), T, 0, stream>>>(rp_bi, cur_bi, NBUc);
  k_scatter1<<<nb(E_bi), T, 0, stream>>>(bi_b, bi_i, E_bi, cur_bi, col_bi);

  // ---------------- IL propagate (users+items) ----------------
  k_dinv_rp<<<nb(NILc), T, 0, stream>>>(rp_ui, DINV, NILc);
  k_spmm_csr<<<(NILc + 3) / 4, T, 0, stream>>>(rp_ui, col_ui, DINV, userF, itemF, NUc,
                                               F1, 0.5f, NILc);
  k_rownorm_inv<<<(NILc + 3) / 4, T, 0, stream>>>(F1, INV1, NILc);
  k_spmm_csr<<<(NILc + 3) / 4, T, 0, stream>>>(rp_ui, col_ui, DINV, F1, F1 + (size_t)NUc * 64,
                                               NUc, F2, 1.0f / 3.0f, NILc);
  k_rownorm_inv<<<(NILc + 3) / 4, T, 0, stream>>>(F2, INV2, NILc);
  k_acc<<<nb((long)NILc * 64), T, 0, stream>>>(userF, itemF, NUc, NILc, F1, INV1, F2, INV2, ACC);
  k_gather<<<nb((long)B * 64), T, 0, stream>>>(users, B, ACC, 0, ILu);

  // bundle aggregation from IL item embeddings
  k_agg_csr<<<(NBUc + 3) / 4, T, 0, stream>>>(rp_bi, col_bi, ACC + (size_t)NUc * 64, ILB, NBUc);
  k_gather<<<nb((long)2 * B * 64), T, 0, stream>>>(bundles, 2 * B, ILB, 0, ILb2);

  // ---------------- BL propagate (users+bundles) ----------------
  k_dinv_rp<<<nb(NBLc), T, 0, stream>>>(rp_ub, DINV, NBLc);
  k_spmm_csr<<<(NBLc + 3) / 4, T, 0, stream>>>(rp_ub, col_ub, DINV, userF, bundF, NUc,
                                               F1, 0.5f, NBLc);
  k_rownorm_inv<<<(NBLc + 3) / 4, T, 0, stream>>>(F1, INV1, NBLc);
  k_spmm_csr<<<(NBLc + 3) / 4, T, 0, stream>>>(rp_ub, col_ub, DINV, F1, F1 + (size_t)NUc * 64,
                                               NUc, F2, 1.0f / 3.0f, NBLc);
  k_rownorm_inv<<<(NBLc + 3) / 4, T, 0, stream>>>(F2, INV2, NBLc);
  k_acc<<<nb((long)NBLc * 64), T, 0, stream>>>(userF, bundF, NUc, NBLc, F1, INV1, F2, INV2, ACC);
  k_gather<<<nb((long)B * 64), T, 0, stream>>>(users, B, ACC, 0, BLu);
  k_gather<<<nb((long)2 * B * 64), T, 0, stream>>>(bundles, 2 * B, ACC, NUc, BLb2);

  // ---------------- losses ----------------
  hipMemsetAsync(out, 0, 2 * sizeof(float), stream);
  k_bpr<<<(B + 3) / 4, T, 0, stream>>>(ILu, ILb2, BLu, BLb2, B, out);

  k_normalize<<<(B + 3) / 4, T, 0, stream>>>(ILu, 64, PN, B);
  k_normalize<<<(B + 3) / 4, T, 0, stream>>>(BLu, 64, AN, B);
  k_closs<<<B, 256, 0, stream>>>(PN, AN, B, 0.5f / (float)B, out);

  k_normalize<<<(B + 3) / 4, T, 0, stream>>>(ILb2, 128, PN, B);
  k_normalize<<<(B + 3) / 4, T, 0, stream>>>(BLb2, 128, AN, B);
  k_closs<<<B, 256, 0, stream>>>(PN, AN, B, 0.5f / (float)B, out);
}

// Round 4
// 1253.434 us; speedup vs baseline: 2.4177x; 1.3551x over previous
//
#include <hip/hip_runtime.h>
#include <hip/hip_bf16.h>
#include <math.h>

// CrossCBR: two L=2 graph propagations + bundle agg + BPR/InfoNCE losses.
// R4: bucketed CSR build (line-dense writes) replacing counting-sort scatter
// whose random 4B writes caused 16x write amplification (187MB for 12MB col).
static constexpr int NUc  = 50000;
static constexpr int NBUc = 20000;
static constexpr int NIc  = 100000;
static constexpr int NILc = NUc + NIc;   // 150000 nodes in user-item graph
static constexpr int NBLc = NUc + NBUc;  // 70000 nodes in user-bundle graph

__device__ __forceinline__ float wredsum(float v) {
  #pragma unroll
  for (int m = 32; m >= 1; m >>= 1) v += __shfl_xor(v, m, 64);
  return v;
}

// ---------------- bucketed CSR build ----------------
// Bucket = row >> shift, span (1<<shift) <= 512 rows, nbuck <= 512.

// pass 0: bucket counts. Grid-stride chunks, LDS hist, one flush per block.
__global__ void k_bcount_sym(const int* __restrict__ eu, const int* __restrict__ ex,
                             int E, int off, int shift, int nbuck, int* __restrict__ bCnt) {
  __shared__ int hist[512];
  int chunk = (E + gridDim.x - 1) / gridDim.x;
  int c0 = blockIdx.x * chunk, c1 = min(E, c0 + chunk);
  for (int i = threadIdx.x; i < nbuck; i += blockDim.x) hist[i] = 0;
  __syncthreads();
  for (int e = c0 + threadIdx.x; e < c1; e += blockDim.x) {
    atomicAdd(&hist[eu[e] >> shift], 1);
    atomicAdd(&hist[(ex[e] + off) >> shift], 1);
  }
  __syncthreads();
  for (int i = threadIdx.x; i < nbuck; i += blockDim.x)
    if (hist[i]) atomicAdd(&bCnt[i], hist[i]);
}

__global__ void k_bcount_dir(const int* __restrict__ er, int E, int shift, int nbuck,
                             int* __restrict__ bCnt) {
  __shared__ int hist[512];
  int chunk = (E + gridDim.x - 1) / gridDim.x;
  int c0 = blockIdx.x * chunk, c1 = min(E, c0 + chunk);
  for (int i = threadIdx.x; i < nbuck; i += blockDim.x) hist[i] = 0;
  __syncthreads();
  for (int e = c0 + threadIdx.x; e < c1; e += blockDim.x)
    atomicAdd(&hist[er[e] >> shift], 1);
  __syncthreads();
  for (int i = threadIdx.x; i < nbuck; i += blockDim.x)
    if (hist[i]) atomicAdd(&bCnt[i], hist[i]);
}

// exclusive scan of bCnt[0..n) -> bBase[0..n], copy into bCur. n <= 512, 1 block of 512.
__global__ void k_scan512(const int* __restrict__ data, int n, int* __restrict__ outBase,
                          int* __restrict__ outCur) {
  __shared__ int sh[512];
  int t = threadIdx.x;
  int v = (t < n) ? data[t] : 0;
  sh[t] = v;
  __syncthreads();
  for (int o = 1; o < 512; o <<= 1) {
    int x = (t >= o) ? sh[t - o] : 0;
    __syncthreads();
    sh[t] += x;
    __syncthreads();
  }
  int excl = sh[t] - v;
  if (t < n) { outBase[t] = excl; outCur[t] = excl; }
  if (t == n - 1) outBase[n] = sh[t];
}

// pass A: binning. Two-phase per block: LDS count -> reserve global ranges -> emit.
// Writes are appends behind ~nbuck cursors => line-dense.
__global__ void k_bin_sym(const int* __restrict__ eu, const int* __restrict__ ex,
                          int E, int off, int shift, int nbuck,
                          int* __restrict__ bCur, int2* __restrict__ binned) {
  __shared__ int hist[512];
  __shared__ int base[512];
  int chunk = (E + gridDim.x - 1) / gridDim.x;
  int c0 = blockIdx.x * chunk, c1 = min(E, c0 + chunk);
  for (int i = threadIdx.x; i < nbuck; i += blockDim.x) hist[i] = 0;
  __syncthreads();
  for (int e = c0 + threadIdx.x; e < c1; e += blockDim.x) {
    atomicAdd(&hist[eu[e] >> shift], 1);
    atomicAdd(&hist[(ex[e] + off) >> shift], 1);
  }
  __syncthreads();
  for (int i = threadIdx.x; i < nbuck; i += blockDim.x) {
    int h = hist[i];
    base[i] = h ? atomicAdd(&bCur[i], h) : 0;
    hist[i] = 0;  // becomes local cursor
  }
  __syncthreads();
  for (int e = c0 + threadIdx.x; e < c1; e += blockDim.x) {
    int u = eu[e], x = ex[e] + off;
    int b1 = u >> shift;
    int p1 = base[b1] + atomicAdd(&hist[b1], 1);
    binned[p1] = make_int2(u, x);
    int b2 = x >> shift;
    int p2 = base[b2] + atomicAdd(&hist[b2], 1);
    binned[p2] = make_int2(x, u);
  }
}

__global__ void k_bin_dir(const int* __restrict__ er, const int* __restrict__ ec,
                          int E, int shift, int nbuck,
                          int* __restrict__ bCur, int2* __restrict__ binned) {
  __shared__ int hist[512];
  __shared__ int base[512];
  int chunk = (E + gridDim.x - 1) / gridDim.x;
  int c0 = blockIdx.x * chunk, c1 = min(E, c0 + chunk);
  for (int i = threadIdx.x; i < nbuck; i += blockDim.x) hist[i] = 0;
  __syncthreads();
  for (int e = c0 + threadIdx.x; e < c1; e += blockDim.x)
    atomicAdd(&hist[er[e] >> shift], 1);
  __syncthreads();
  for (int i = threadIdx.x; i < nbuck; i += blockDim.x) {
    int h = hist[i];
    base[i] = h ? atomicAdd(&bCur[i], h) : 0;
    hist[i] = 0;
  }
  __syncthreads();
  for (int e = c0 + threadIdx.x; e < c1; e += blockDim.x) {
    int r = er[e];
    int b1 = r >> shift;
    int p1 = base[b1] + atomicAdd(&hist[b1], 1);
    binned[p1] = make_int2(r, ec[e]);
  }
}

// pass B: per-bucket row histogram -> dense cnt segment
__global__ void k_rowhist(const int2* __restrict__ binned, const int* __restrict__ bBase,
                          int shift, int n, int* __restrict__ cnt) {
  __shared__ int hist[512];
  int b = blockIdx.x;
  int span = 1 << shift;
  int rowbase = b << shift;
  int s = bBase[b], e = bBase[b + 1];
  for (int i = threadIdx.x; i < span; i += blockDim.x) hist[i] = 0;
  __syncthreads();
  for (int i = s + threadIdx.x; i < e; i += blockDim.x)
    atomicAdd(&hist[binned[i].x - rowbase], 1);
  __syncthreads();
  for (int i = threadIdx.x; i < span; i += blockDim.x) {
    int row = rowbase + i;
    if (row < n) cnt[row] = hist[i];
  }
}

// pass D: per-bucket CSR fill; writes confined to bucket's contiguous col range
__global__ void k_csrfill(const int2* __restrict__ binned, const int* __restrict__ bBase,
                          int shift, int n, const int* __restrict__ rp, int* __restrict__ colv) {
  __shared__ int cur[512];
  int b = blockIdx.x;
  int span = 1 << shift;
  int rowbase = b << shift;
  int s = bBase[b], e = bBase[b + 1];
  for (int i = threadIdx.x; i < span; i += blockDim.x) {
    int row = rowbase + i;
    cur[i] = (row < n) ? rp[row] : 0;
  }
  __syncthreads();
  for (int i = s + threadIdx.x; i < e; i += blockDim.x) {
    int2 rc = binned[i];
    int pos = atomicAdd(&cur[rc.x - rowbase], 1);
    colv[pos] = rc.y;
  }
}

// hierarchical exclusive scan: block of 256 covers 1024 elements
__global__ void k_scan_block(const int* __restrict__ in, int n, int* __restrict__ out,
                             int* __restrict__ bsum) {
  __shared__ int sh[256];
  int t = threadIdx.x;
  long base = (long)blockIdx.x * 1024 + (long)t * 4;
  int v0 = (base     < n) ? in[base]     : 0;
  int v1 = (base + 1 < n) ? in[base + 1] : 0;
  int v2 = (base + 2 < n) ? in[base + 2] : 0;
  int v3 = (base + 3 < n) ? in[base + 3] : 0;
  int tsum = v0 + v1 + v2 + v3;
  sh[t] = tsum;
  __syncthreads();
  for (int o = 1; o < 256; o <<= 1) {
    int x = (t >= o) ? sh[t - o] : 0;
    __syncthreads();
    sh[t] += x;
    __syncthreads();
  }
  int excl = sh[t] - tsum;
  if (t == 255) bsum[blockIdx.x] = sh[255];
  if (base     < n) out[base]     = excl;
  if (base + 1 < n) out[base + 1] = excl + v0;
  if (base + 2 < n) out[base + 2] = excl + v0 + v1;
  if (base + 3 < n) out[base + 3] = excl + v0 + v1 + v2;
}

__global__ void k_scan_bsum(int* __restrict__ bsum, int nb) {  // nb <= 256
  __shared__ int sh[256];
  int t = threadIdx.x;
  int v = (t < nb) ? bsum[t] : 0;
  sh[t] = v;
  __syncthreads();
  for (int o = 1; o < 256; o <<= 1) {
    int x = (t >= o) ? sh[t - o] : 0;
    __syncthreads();
    sh[t] += x;
    __syncthreads();
  }
  if (t < nb) bsum[t] = sh[t] - v;
}

__global__ void k_scan_add(int* __restrict__ out, int n, const int* __restrict__ bsum) {
  long i = (long)blockIdx.x * blockDim.x + threadIdx.x;
  if (i < n) out[i] += bsum[i >> 10];
}

__global__ void k_dinv_rp(const int* __restrict__ rp, float* __restrict__ dinv, int n) {
  int i = blockIdx.x * blockDim.x + threadIdx.x;
  if (i >= n) return;
  float d = (float)(rp[i + 1] - rp[i]);
  dinv[i] = 1.0f / (sqrtf(d) + 1e-8f);
}

// ---------------- gather SpMM ----------------
__global__ void k_spmm_csr(const int* __restrict__ rp, const int* __restrict__ col,
                           const float* __restrict__ dinv,
                           const float* __restrict__ fA, const float* __restrict__ fB,
                           int off, float* __restrict__ out, float scale, int n) {
  int row = blockIdx.x * (blockDim.x >> 6) + (threadIdx.x >> 6);
  int lane = threadIdx.x & 63;
  if (row >= n) return;
  int s = rp[row], e = rp[row + 1];
  float acc = 0.0f;
  for (int chunk = s; chunk < e; chunk += 64) {
    int nc = min(64, e - chunk);
    int ci = 0; float dv = 0.0f;
    if (lane < nc) { ci = col[chunk + lane]; dv = dinv[ci]; }
    int j = 0;
    for (; j + 2 <= nc; j += 2) {
      int c0 = __shfl(ci, j, 64);     float v0 = __shfl(dv, j, 64);
      int c1 = __shfl(ci, j + 1, 64); float v1 = __shfl(dv, j + 1, 64);
      const float* s0 = (c0 < off) ? fA + (long)c0 * 64 : fB + ((long)c0 - off) * 64;
      const float* s1 = (c1 < off) ? fA + (long)c1 * 64 : fB + ((long)c1 - off) * 64;
      float x0 = s0[lane];
      float x1 = s1[lane];
      acc = fmaf(v0, x0, acc);
      acc = fmaf(v1, x1, acc);
    }
    if (j < nc) {
      int c0 = __shfl(ci, j, 64); float v0 = __shfl(dv, j, 64);
      const float* s0 = (c0 < off) ? fA + (long)c0 * 64 : fB + ((long)c0 - off) * 64;
      acc = fmaf(v0, s0[lane], acc);
    }
  }
  out[(long)row * 64 + lane] = acc * (dinv[row] * scale);
}

__global__ void k_agg_csr(const int* __restrict__ rp, const int* __restrict__ col,
                          const float* __restrict__ src, float* __restrict__ out, int n) {
  int row = blockIdx.x * (blockDim.x >> 6) + (threadIdx.x >> 6);
  int lane = threadIdx.x & 63;
  if (row >= n) return;
  int s = rp[row], e = rp[row + 1];
  float acc = 0.0f;
  for (int chunk = s; chunk < e; chunk += 64) {
    int nc = min(64, e - chunk);
    int ci = 0;
    if (lane < nc) ci = col[chunk + lane];
    for (int j = 0; j < nc; j++) {
      int c0 = __shfl(ci, j, 64);
      acc += src[(long)c0 * 64 + lane];
    }
  }
  float w = 1.0f / ((float)(e - s) + 1e-8f);
  out[(long)row * 64 + lane] = acc * w;
}

// ---------------- misc ----------------
__global__ void k_rownorm_inv(const float* __restrict__ f, float* __restrict__ inv, int n) {
  int row = blockIdx.x * (blockDim.x >> 6) + (threadIdx.x >> 6);
  int lane = threadIdx.x & 63;
  if (row >= n) return;
  float v = f[(long)row * 64 + lane];
  float s = wredsum(v * v);
  if (lane == 0) inv[row] = 1.0f / fmaxf(sqrtf(s), 1e-12f);
}

__global__ void k_acc(const float* __restrict__ fA, const float* __restrict__ fB, int off, int n,
                      const float* __restrict__ F1, const float* __restrict__ inv1,
                      const float* __restrict__ F2, const float* __restrict__ inv2,
                      float* __restrict__ acc) {
  long idx = (long)blockIdx.x * blockDim.x + threadIdx.x;
  if (idx >= (long)n * 64) return;
  int r = (int)(idx >> 6);
  float base = (r < off) ? fA[idx] : fB[idx - (long)off * 64];
  acc[idx] = base + F1[idx] * inv1[r] + F2[idx] * inv2[r];
}

__global__ void k_gather(const int* __restrict__ idx, int nrow, const float* __restrict__ src,
                         int srcOff, float* __restrict__ dst) {
  long i = (long)blockIdx.x * blockDim.x + threadIdx.x;
  if (i >= (long)nrow * 64) return;
  int r = (int)(i >> 6);
  int d = (int)(i & 63);
  dst[i] = src[(long)(idx[r] + srcOff) * 64 + d];
}

__global__ void k_normalize(const float* __restrict__ src, int stride, float* __restrict__ dst, int n) {
  int row = blockIdx.x * (blockDim.x >> 6) + (threadIdx.x >> 6);
  int lane = threadIdx.x & 63;
  if (row >= n) return;
  float v = src[(long)row * stride + lane];
  float s = wredsum(v * v);
  float inv = 1.0f / fmaxf(sqrtf(s), 1e-12f);
  dst[(long)row * 64 + lane] = v * inv;
}

__global__ void k_bpr(const float* __restrict__ ILu, const float* __restrict__ ILb2,
                      const float* __restrict__ BLu, const float* __restrict__ BLb2,
                      int B, float* __restrict__ out) {
  int row = blockIdx.x * (blockDim.x >> 6) + (threadIdx.x >> 6);
  int lane = threadIdx.x & 63;
  if (row >= B) return;
  float t = ILu[(long)row * 64 + lane] *
              (ILb2[(long)(2 * row) * 64 + lane] - ILb2[(long)(2 * row + 1) * 64 + lane]) +
            BLu[(long)row * 64 + lane] *
              (BLb2[(long)(2 * row) * 64 + lane] - BLb2[(long)(2 * row + 1) * 64 + lane]);
  float x = wredsum(t);
  if (lane == 0) {
    float ls = -(fmaxf(-x, 0.0f) + log1pf(expf(-fabsf(x))));
    unsafeAtomicAdd(&out[0], -ls / (float)B);
  }
}

__global__ void k_closs(const float* __restrict__ P, const float* __restrict__ A, int B,
                        float coeffOverB, float* __restrict__ out) {
  __shared__ float Psh[64];
  __shared__ float sm[256];
  __shared__ float ss[256];
  __shared__ float sdiag;
  int r = blockIdx.x;
  int t = threadIdx.x;
  if (t < 64) Psh[t] = P[(long)r * 64 + t];
  __syncthreads();
  float m = -1e30f, s = 0.0f;
  for (int c = t; c < B; c += 256) {
    const float4* a4 = (const float4*)(A + (long)c * 64);
    float dot = 0.0f;
    #pragma unroll
    for (int q = 0; q < 16; q++) {
      float4 av = a4[q];
      dot += Psh[4 * q] * av.x + Psh[4 * q + 1] * av.y + Psh[4 * q + 2] * av.z + Psh[4 * q + 3] * av.w;
    }
    float x = dot * 4.0f;  // 1/C_TEMP
    if (c == r) sdiag = x;
    if (x > m) { s = s * expf(m - x) + 1.0f; m = x; }
    else       { s += expf(x - m); }
  }
  sm[t] = m; ss[t] = s;
  __syncthreads();
  for (int w = 128; w >= 1; w >>= 1) {
    if (t < w) {
      float m2 = sm[t + w], s2 = ss[t + w];
      float M = fmaxf(sm[t], m2);
      ss[t] = ss[t] * expf(sm[t] - M) + s2 * expf(m2 - M);
      sm[t] = M;
    }
    __syncthreads();
  }
  if (t == 0) {
    float lse = sm[0] + logf(ss[0]);
    unsafeAtomicAdd(&out[1], -(sdiag - lse) * coeffOverB);
  }
}

extern "C" void kernel_launch(void* const* d_in, const int* in_sizes, int n_in,
                              void* d_out, int out_size, void* d_ws, size_t ws_size,
                              hipStream_t stream) {
  const int* users   = (const int*)d_in[0];
  const int* bundles = (const int*)d_in[1];
  const int* ui_u    = (const int*)d_in[2];
  const int* ui_i    = (const int*)d_in[3];
  const int* ub_u    = (const int*)d_in[4];
  const int* ub_b    = (const int*)d_in[5];
  const int* bi_b    = (const int*)d_in[6];
  const int* bi_i    = (const int*)d_in[7];
  const float* userF = (const float*)d_in[8];
  const float* bundF = (const float*)d_in[9];
  const float* itemF = (const float*)d_in[10];
  float* out = (float*)d_out;

  const int B    = in_sizes[0];
  const int E_ui = in_sizes[2];
  const int E_ub = in_sizes[4];
  const int E_bi = in_sizes[6];

  float* ws = (float*)d_ws;
  size_t off = 0;
  auto alloc = [&](size_t nfloat) -> float* {
    float* p = ws + off;
    off += (nfloat + 63) & ~(size_t)63;
    return p;
  };
  float* F1   = alloc((size_t)NILc * 64);
  float* F2   = alloc((size_t)NILc * 64);
  float* ACC  = alloc((size_t)NILc * 64);
  float* DINV = alloc(NILc);
  float* INV1 = alloc(NILc);
  float* INV2 = alloc(NILc);
  float* ILB  = alloc((size_t)NBUc * 64);
  float* ILu  = alloc((size_t)B * 64);
  float* BLu  = alloc((size_t)B * 64);
  float* ILb2 = alloc((size_t)B * 128);
  float* BLb2 = alloc((size_t)B * 128);
  float* PN   = alloc((size_t)B * 64);
  float* AN   = alloc((size_t)B * 64);
  // CSR buffers
  int* rp_ui  = (int*)alloc(NILc + 1);
  int* col_ui = (int*)alloc(2 * (size_t)E_ui);
  int* rp_ub  = (int*)alloc(NBLc + 1);
  int* col_ub = (int*)alloc(2 * (size_t)E_ub);
  int* rp_bi  = (int*)alloc(NBUc + 1);
  int* col_bi = (int*)alloc((size_t)E_bi);
  int* cntS   = (int*)alloc(NILc + 1);   // shared row-count scratch
  int* bCnt   = (int*)alloc(1024);
  int* bBase  = (int*)alloc(1024);
  int* bCur   = (int*)alloc(1024);
  int* bsum   = (int*)alloc(256);
  (void)ws_size; (void)n_in; (void)out_size;

  const int T = 256;
  auto nb = [&](long total) { return (int)((total + T - 1) / T); };

  auto scan_finish = [&](int* cnt, int* rp, int scan_n) {
    int nb1 = (scan_n + 1023) / 1024;
    k_scan_block<<<nb1, 256, 0, stream>>>(cnt, scan_n, rp, bsum);
    k_scan_bsum<<<1, 256, 0, stream>>>(bsum, nb1);
    k_scan_add<<<(scan_n + 255) / 256, 256, 0, stream>>>(rp, scan_n, bsum);
  };

  // Binned (row,col) pair scratch overlays dead phases of F1/F2:
  //   UI build -> F1 (24MB <= 38.4MB), before IL spmm1 writes F1
  //   BI build -> F2 (8MB),  before IL spmm2 writes F2
  //   UB build -> F1 (16MB), after IL k_acc (last F1 read), before BL spmm1

  // ---- UI CSR: n=150000, shift=9, nbuck=293 ----
  {
    const int SH = 9, NBK = (NILc + (1 << SH) - 1) >> SH;  // 293
    int2* binned = (int2*)F1;
    hipMemsetAsync(bCnt, 0, sizeof(int) * NBK, stream);
    k_bcount_sym<<<1024, T, 0, stream>>>(ui_u, ui_i, E_ui, NUc, SH, NBK, bCnt);
    k_scan512<<<1, 512, 0, stream>>>(bCnt, NBK, bBase, bCur);
    k_bin_sym<<<1024, T, 0, stream>>>(ui_u, ui_i, E_ui, NUc, SH, NBK, bCur, binned);
    hipMemsetAsync(cntS, 0, sizeof(int) * (NILc + 1), stream);
    k_rowhist<<<NBK, T, 0, stream>>>(binned, bBase, SH, NILc, cntS);
    scan_finish(cntS, rp_ui, NILc + 1);
    k_csrfill<<<NBK, T, 0, stream>>>(binned, bBase, SH, NILc, rp_ui, col_ui);
  }

  // ---- BI CSR: n=20000, shift=6, nbuck=313 ----
  {
    const int SH = 6, NBK = (NBUc + (1 << SH) - 1) >> SH;  // 313
    int2* binned = (int2*)F2;
    hipMemsetAsync(bCnt, 0, sizeof(int) * NBK, stream);
    k_bcount_dir<<<1024, T, 0, stream>>>(bi_b, E_bi, SH, NBK, bCnt);
    k_scan512<<<1, 512, 0, stream>>>(bCnt, NBK, bBase, bCur);
    k_bin_dir<<<1024, T, 0, stream>>>(bi_b, bi_i, E_bi, SH, NBK, bCur, binned);
    hipMemsetAsync(cntS, 0, sizeof(int) * (NBUc + 1), stream);
    k_rowhist<<<NBK, T, 0, stream>>>(binned, bBase, SH, NBUc, cntS);
    scan_finish(cntS, rp_bi, NBUc + 1);
    k_csrfill<<<NBK, T, 0, stream>>>(binned, bBase, SH, NBUc, rp_bi, col_bi);
  }

  // ---------------- IL propagate (users+items) ----------------
  k_dinv_rp<<<nb(NILc), T, 0, stream>>>(rp_ui, DINV, NILc);
  k_spmm_csr<<<(NILc + 3) / 4, T, 0, stream>>>(rp_ui, col_ui, DINV, userF, itemF, NUc,
                                               F1, 0.5f, NILc);
  k_rownorm_inv<<<(NILc + 3) / 4, T, 0, stream>>>(F1, INV1, NILc);
  k_spmm_csr<<<(NILc + 3) / 4, T, 0, stream>>>(rp_ui, col_ui, DINV, F1, F1 + (size_t)NUc * 64,
                                               NUc, F2, 1.0f / 3.0f, NILc);
  k_rownorm_inv<<<(NILc + 3) / 4, T, 0, stream>>>(F2, INV2, NILc);
  k_acc<<<nb((long)NILc * 64), T, 0, stream>>>(userF, itemF, NUc, NILc, F1, INV1, F2, INV2, ACC);
  k_gather<<<nb((long)B * 64), T, 0, stream>>>(users, B, ACC, 0, ILu);

  // bundle aggregation from IL item embeddings
  k_agg_csr<<<(NBUc + 3) / 4, T, 0, stream>>>(rp_bi, col_bi, ACC + (size_t)NUc * 64, ILB, NBUc);
  k_gather<<<nb((long)2 * B * 64), T, 0, stream>>>(bundles, 2 * B, ILB, 0, ILb2);

  // ---- UB CSR: n=70000, shift=8, nbuck=274 (F1 now dead until BL spmm1) ----
  {
    const int SH = 8, NBK = (NBLc + (1 << SH) - 1) >> SH;  // 274
    int2* binned = (int2*)F1;
    hipMemsetAsync(bCnt, 0, sizeof(int) * NBK, stream);
    k_bcount_sym<<<1024, T, 0, stream>>>(ub_u, ub_b, E_ub, NUc, SH, NBK, bCnt);
    k_scan512<<<1, 512, 0, stream>>>(bCnt, NBK, bBase, bCur);
    k_bin_sym<<<1024, T, 0, stream>>>(ub_u, ub_b, E_ub, NUc, SH, NBK, bCur, binned);
    hipMemsetAsync(cntS, 0, sizeof(int) * (NBLc + 1), stream);
    k_rowhist<<<NBK, T, 0, stream>>>(binned, bBase, SH, NBLc, cntS);
    scan_finish(cntS, rp_ub, NBLc + 1);
    k_csrfill<<<NBK, T, 0, stream>>>(binned, bBase, SH, NBLc, rp_ub, col_ub);
  }

  // ---------------- BL propagate (users+bundles) ----------------
  k_dinv_rp<<<nb(NBLc), T, 0, stream>>>(rp_ub, DINV, NBLc);
  k_spmm_csr<<<(NBLc + 3) / 4, T, 0, stream>>>(rp_ub, col_ub, DINV, userF, bundF, NUc,
                                               F1, 0.5f, NBLc);
  k_rownorm_inv<<<(NBLc + 3) / 4, T, 0, stream>>>(F1, INV1, NBLc);
  k_spmm_csr<<<(NBLc + 3) / 4, T, 0, stream>>>(rp_ub, col_ub, DINV, F1, F1 + (size_t)NUc * 64,
                                               NUc, F2, 1.0f / 3.0f, NBLc);
  k_rownorm_inv<<<(NBLc + 3) / 4, T, 0, stream>>>(F2, INV2, NBLc);
  k_acc<<<nb((long)NBLc * 64), T, 0, stream>>>(userF, bundF, NUc, NBLc, F1, INV1, F2, INV2, ACC);
  k_gather<<<nb((long)B * 64), T, 0, stream>>>(users, B, ACC, 0, BLu);
  k_gather<<<nb((long)2 * B * 64), T, 0, stream>>>(bundles, 2 * B, ACC, NUc, BLb2);

  // ---------------- losses ----------------
  hipMemsetAsync(out, 0, 2 * sizeof(float), stream);
  k_bpr<<<(B + 3) / 4, T, 0, stream>>>(ILu, ILb2, BLu, BLb2, B, out);

  k_normalize<<<(B + 3) / 4, T, 0, stream>>>(ILu, 64, PN, B);
  k_normalize<<<(B + 3) / 4, T, 0, stream>>>(BLu, 64, AN, B);
  k_closs<<<B, 256, 0, stream>>>(PN, AN, B, 0.5f / (float)B, out);

  k_normalize<<<(B + 3) / 4, T, 0, stream>>>(ILb2, 128, PN, B);
  k_normalize<<<(B + 3) / 4, T, 0, stream>>>(BLb2, 128, AN, B);
  k_closs<<<B, 256, 0, stream>>>(PN, AN, B, 0.5f / (float)B, out);
}

// Round 5
// 1064.413 us; speedup vs baseline: 2.8470x; 1.1776x over previous
//
#include <hip/hip_runtime.h>
#include <hip/hip_bf16.h>
#include <math.h>

// CrossCBR: two L=2 graph propagations + bundle agg + BPR/InfoNCE losses.
// R5: replace latency-bound fused k_closs (152us: strided L2 gathers, L1-miss
// bound) with tiled fp32 GEMM (S = Pn*An^T/tau) + row-wise online LSE pass.
static constexpr int NUc  = 50000;
static constexpr int NBUc = 20000;
static constexpr int NIc  = 100000;
static constexpr int NILc = NUc + NIc;   // 150000 nodes in user-item graph
static constexpr int NBLc = NUc + NBUc;  // 70000 nodes in user-bundle graph

__device__ __forceinline__ float wredsum(float v) {
  #pragma unroll
  for (int m = 32; m >= 1; m >>= 1) v += __shfl_xor(v, m, 64);
  return v;
}

// ---------------- bucketed CSR build ----------------
__global__ void k_bcount_sym(const int* __restrict__ eu, const int* __restrict__ ex,
                             int E, int off, int shift, int nbuck, int* __restrict__ bCnt) {
  __shared__ int hist[512];
  int chunk = (E + gridDim.x - 1) / gridDim.x;
  int c0 = blockIdx.x * chunk, c1 = min(E, c0 + chunk);
  for (int i = threadIdx.x; i < nbuck; i += blockDim.x) hist[i] = 0;
  __syncthreads();
  for (int e = c0 + threadIdx.x; e < c1; e += blockDim.x) {
    atomicAdd(&hist[eu[e] >> shift], 1);
    atomicAdd(&hist[(ex[e] + off) >> shift], 1);
  }
  __syncthreads();
  for (int i = threadIdx.x; i < nbuck; i += blockDim.x)
    if (hist[i]) atomicAdd(&bCnt[i], hist[i]);
}

__global__ void k_bcount_dir(const int* __restrict__ er, int E, int shift, int nbuck,
                             int* __restrict__ bCnt) {
  __shared__ int hist[512];
  int chunk = (E + gridDim.x - 1) / gridDim.x;
  int c0 = blockIdx.x * chunk, c1 = min(E, c0 + chunk);
  for (int i = threadIdx.x; i < nbuck; i += blockDim.x) hist[i] = 0;
  __syncthreads();
  for (int e = c0 + threadIdx.x; e < c1; e += blockDim.x)
    atomicAdd(&hist[er[e] >> shift], 1);
  __syncthreads();
  for (int i = threadIdx.x; i < nbuck; i += blockDim.x)
    if (hist[i]) atomicAdd(&bCnt[i], hist[i]);
}

__global__ void k_scan512(const int* __restrict__ data, int n, int* __restrict__ outBase,
                          int* __restrict__ outCur) {
  __shared__ int sh[512];
  int t = threadIdx.x;
  int v = (t < n) ? data[t] : 0;
  sh[t] = v;
  __syncthreads();
  for (int o = 1; o < 512; o <<= 1) {
    int x = (t >= o) ? sh[t - o] : 0;
    __syncthreads();
    sh[t] += x;
    __syncthreads();
  }
  int excl = sh[t] - v;
  if (t < n) { outBase[t] = excl; outCur[t] = excl; }
  if (t == n - 1) outBase[n] = sh[t];
}

__global__ void k_bin_sym(const int* __restrict__ eu, const int* __restrict__ ex,
                          int E, int off, int shift, int nbuck,
                          int* __restrict__ bCur, int2* __restrict__ binned) {
  __shared__ int hist[512];
  __shared__ int base[512];
  int chunk = (E + gridDim.x - 1) / gridDim.x;
  int c0 = blockIdx.x * chunk, c1 = min(E, c0 + chunk);
  for (int i = threadIdx.x; i < nbuck; i += blockDim.x) hist[i] = 0;
  __syncthreads();
  for (int e = c0 + threadIdx.x; e < c1; e += blockDim.x) {
    atomicAdd(&hist[eu[e] >> shift], 1);
    atomicAdd(&hist[(ex[e] + off) >> shift], 1);
  }
  __syncthreads();
  for (int i = threadIdx.x; i < nbuck; i += blockDim.x) {
    int h = hist[i];
    base[i] = h ? atomicAdd(&bCur[i], h) : 0;
    hist[i] = 0;
  }
  __syncthreads();
  for (int e = c0 + threadIdx.x; e < c1; e += blockDim.x) {
    int u = eu[e], x = ex[e] + off;
    int b1 = u >> shift;
    int p1 = base[b1] + atomicAdd(&hist[b1], 1);
    binned[p1] = make_int2(u, x);
    int b2 = x >> shift;
    int p2 = base[b2] + atomicAdd(&hist[b2], 1);
    binned[p2] = make_int2(x, u);
  }
}

__global__ void k_bin_dir(const int* __restrict__ er, const int* __restrict__ ec,
                          int E, int shift, int nbuck,
                          int* __restrict__ bCur, int2* __restrict__ binned) {
  __shared__ int hist[512];
  __shared__ int base[512];
  int chunk = (E + gridDim.x - 1) / gridDim.x;
  int c0 = blockIdx.x * chunk, c1 = min(E, c0 + chunk);
  for (int i = threadIdx.x; i < nbuck; i += blockDim.x) hist[i] = 0;
  __syncthreads();
  for (int e = c0 + threadIdx.x; e < c1; e += blockDim.x)
    atomicAdd(&hist[er[e] >> shift], 1);
  __syncthreads();
  for (int i = threadIdx.x; i < nbuck; i += blockDim.x) {
    int h = hist[i];
    base[i] = h ? atomicAdd(&bCur[i], h) : 0;
    hist[i] = 0;
  }
  __syncthreads();
  for (int e = c0 + threadIdx.x; e < c1; e += blockDim.x) {
    int r = er[e];
    int b1 = r >> shift;
    int p1 = base[b1] + atomicAdd(&hist[b1], 1);
    binned[p1] = make_int2(r, ec[e]);
  }
}

__global__ void k_rowhist(const int2* __restrict__ binned, const int* __restrict__ bBase,
                          int shift, int n, int* __restrict__ cnt) {
  __shared__ int hist[512];
  int b = blockIdx.x;
  int span = 1 << shift;
  int rowbase = b << shift;
  int s = bBase[b], e = bBase[b + 1];
  for (int i = threadIdx.x; i < span; i += blockDim.x) hist[i] = 0;
  __syncthreads();
  for (int i = s + threadIdx.x; i < e; i += blockDim.x)
    atomicAdd(&hist[binned[i].x - rowbase], 1);
  __syncthreads();
  for (int i = threadIdx.x; i < span; i += blockDim.x) {
    int row = rowbase + i;
    if (row < n) cnt[row] = hist[i];
  }
}

__global__ void k_csrfill(const int2* __restrict__ binned, const int* __restrict__ bBase,
                          int shift, int n, const int* __restrict__ rp, int* __restrict__ colv) {
  __shared__ int cur[512];
  int b = blockIdx.x;
  int span = 1 << shift;
  int rowbase = b << shift;
  int s = bBase[b], e = bBase[b + 1];
  for (int i = threadIdx.x; i < span; i += blockDim.x) {
    int row = rowbase + i;
    cur[i] = (row < n) ? rp[row] : 0;
  }
  __syncthreads();
  for (int i = s + threadIdx.x; i < e; i += blockDim.x) {
    int2 rc = binned[i];
    int pos = atomicAdd(&cur[rc.x - rowbase], 1);
    colv[pos] = rc.y;
  }
}

__global__ void k_scan_block(const int* __restrict__ in, int n, int* __restrict__ out,
                             int* __restrict__ bsum) {
  __shared__ int sh[256];
  int t = threadIdx.x;
  long base = (long)blockIdx.x * 1024 + (long)t * 4;
  int v0 = (base     < n) ? in[base]     : 0;
  int v1 = (base + 1 < n) ? in[base + 1] : 0;
  int v2 = (base + 2 < n) ? in[base + 2] : 0;
  int v3 = (base + 3 < n) ? in[base + 3] : 0;
  int tsum = v0 + v1 + v2 + v3;
  sh[t] = tsum;
  __syncthreads();
  for (int o = 1; o < 256; o <<= 1) {
    int x = (t >= o) ? sh[t - o] : 0;
    __syncthreads();
    sh[t] += x;
    __syncthreads();
  }
  int excl = sh[t] - tsum;
  if (t == 255) bsum[blockIdx.x] = sh[255];
  if (base     < n) out[base]     = excl;
  if (base + 1 < n) out[base + 1] = excl + v0;
  if (base + 2 < n) out[base + 2] = excl + v0 + v1;
  if (base + 3 < n) out[base + 3] = excl + v0 + v1 + v2;
}

__global__ void k_scan_bsum(int* __restrict__ bsum, int nb) {
  __shared__ int sh[256];
  int t = threadIdx.x;
  int v = (t < nb) ? bsum[t] : 0;
  sh[t] = v;
  __syncthreads();
  for (int o = 1; o < 256; o <<= 1) {
    int x = (t >= o) ? sh[t - o] : 0;
    __syncthreads();
    sh[t] += x;
    __syncthreads();
  }
  if (t < nb) bsum[t] = sh[t] - v;
}

__global__ void k_scan_add(int* __restrict__ out, int n, const int* __restrict__ bsum) {
  long i = (long)blockIdx.x * blockDim.x + threadIdx.x;
  if (i < n) out[i] += bsum[i >> 10];
}

__global__ void k_dinv_rp(const int* __restrict__ rp, float* __restrict__ dinv, int n) {
  int i = blockIdx.x * blockDim.x + threadIdx.x;
  if (i >= n) return;
  float d = (float)(rp[i + 1] - rp[i]);
  dinv[i] = 1.0f / (sqrtf(d) + 1e-8f);
}

// ---------------- gather SpMM ----------------
__global__ void k_spmm_csr(const int* __restrict__ rp, const int* __restrict__ col,
                           const float* __restrict__ dinv,
                           const float* __restrict__ fA, const float* __restrict__ fB,
                           int off, float* __restrict__ out, float scale, int n) {
  int row = blockIdx.x * (blockDim.x >> 6) + (threadIdx.x >> 6);
  int lane = threadIdx.x & 63;
  if (row >= n) return;
  int s = rp[row], e = rp[row + 1];
  float acc = 0.0f;
  for (int chunk = s; chunk < e; chunk += 64) {
    int nc = min(64, e - chunk);
    int ci = 0; float dv = 0.0f;
    if (lane < nc) { ci = col[chunk + lane]; dv = dinv[ci]; }
    int j = 0;
    for (; j + 2 <= nc; j += 2) {
      int c0 = __shfl(ci, j, 64);     float v0 = __shfl(dv, j, 64);
      int c1 = __shfl(ci, j + 1, 64); float v1 = __shfl(dv, j + 1, 64);
      const float* s0 = (c0 < off) ? fA + (long)c0 * 64 : fB + ((long)c0 - off) * 64;
      const float* s1 = (c1 < off) ? fA + (long)c1 * 64 : fB + ((long)c1 - off) * 64;
      float x0 = s0[lane];
      float x1 = s1[lane];
      acc = fmaf(v0, x0, acc);
      acc = fmaf(v1, x1, acc);
    }
    if (j < nc) {
      int c0 = __shfl(ci, j, 64); float v0 = __shfl(dv, j, 64);
      const float* s0 = (c0 < off) ? fA + (long)c0 * 64 : fB + ((long)c0 - off) * 64;
      acc = fmaf(v0, s0[lane], acc);
    }
  }
  out[(long)row * 64 + lane] = acc * (dinv[row] * scale);
}

__global__ void k_agg_csr(const int* __restrict__ rp, const int* __restrict__ col,
                          const float* __restrict__ src, float* __restrict__ out, int n) {
  int row = blockIdx.x * (blockDim.x >> 6) + (threadIdx.x >> 6);
  int lane = threadIdx.x & 63;
  if (row >= n) return;
  int s = rp[row], e = rp[row + 1];
  float acc = 0.0f;
  for (int chunk = s; chunk < e; chunk += 64) {
    int nc = min(64, e - chunk);
    int ci = 0;
    if (lane < nc) ci = col[chunk + lane];
    for (int j = 0; j < nc; j++) {
      int c0 = __shfl(ci, j, 64);
      acc += src[(long)c0 * 64 + lane];
    }
  }
  float w = 1.0f / ((float)(e - s) + 1e-8f);
  out[(long)row * 64 + lane] = acc * w;
}

// ---------------- misc ----------------
__global__ void k_rownorm_inv(const float* __restrict__ f, float* __restrict__ inv, int n) {
  int row = blockIdx.x * (blockDim.x >> 6) + (threadIdx.x >> 6);
  int lane = threadIdx.x & 63;
  if (row >= n) return;
  float v = f[(long)row * 64 + lane];
  float s = wredsum(v * v);
  if (lane == 0) inv[row] = 1.0f / fmaxf(sqrtf(s), 1e-12f);
}

__global__ void k_acc(const float* __restrict__ fA, const float* __restrict__ fB, int off, int n,
                      const float* __restrict__ F1, const float* __restrict__ inv1,
                      const float* __restrict__ F2, const float* __restrict__ inv2,
                      float* __restrict__ acc) {
  long idx = (long)blockIdx.x * blockDim.x + threadIdx.x;
  if (idx >= (long)n * 64) return;
  int r = (int)(idx >> 6);
  float base = (r < off) ? fA[idx] : fB[idx - (long)off * 64];
  acc[idx] = base + F1[idx] * inv1[r] + F2[idx] * inv2[r];
}

__global__ void k_gather(const int* __restrict__ idx, int nrow, const float* __restrict__ src,
                         int srcOff, float* __restrict__ dst) {
  long i = (long)blockIdx.x * blockDim.x + threadIdx.x;
  if (i >= (long)nrow * 64) return;
  int r = (int)(i >> 6);
  int d = (int)(i & 63);
  dst[i] = src[(long)(idx[r] + srcOff) * 64 + d];
}

__global__ void k_normalize(const float* __restrict__ src, int stride, float* __restrict__ dst, int n) {
  int row = blockIdx.x * (blockDim.x >> 6) + (threadIdx.x >> 6);
  int lane = threadIdx.x & 63;
  if (row >= n) return;
  float v = src[(long)row * stride + lane];
  float s = wredsum(v * v);
  float inv = 1.0f / fmaxf(sqrtf(s), 1e-12f);
  dst[(long)row * 64 + lane] = v * inv;
}

__global__ void k_bpr(const float* __restrict__ ILu, const float* __restrict__ ILb2,
                      const float* __restrict__ BLu, const float* __restrict__ BLb2,
                      int B, float* __restrict__ out) {
  int row = blockIdx.x * (blockDim.x >> 6) + (threadIdx.x >> 6);
  int lane = threadIdx.x & 63;
  if (row >= B) return;
  float t = ILu[(long)row * 64 + lane] *
              (ILb2[(long)(2 * row) * 64 + lane] - ILb2[(long)(2 * row + 1) * 64 + lane]) +
            BLu[(long)row * 64 + lane] *
              (BLb2[(long)(2 * row) * 64 + lane] - BLb2[(long)(2 * row + 1) * 64 + lane]);
  float x = wredsum(t);
  if (lane == 0) {
    float ls = -(fmaxf(-x, 0.0f) + log1pf(expf(-fabsf(x))));
    unsafeAtomicAdd(&out[0], -ls / (float)B);
  }
}

// ---------------- InfoNCE: tiled GEMM + row LSE ----------------
// S[M][N] = scale * P(M x 64) . A^T(N x 64)
__global__ void k_gemm_nt(const float* __restrict__ P, const float* __restrict__ A,
                          float* __restrict__ S, int M, int N, float scale) {
  __shared__ float Ps[64][129];  // Ps[k][i] = P[bi0+i][k]
  __shared__ float As[64][129];
  int bi0 = blockIdx.y * 128, bj0 = blockIdx.x * 128;
  int t = threadIdx.x;  // 256
  #pragma unroll
  for (int sct = 0; sct < 8; sct++) {
    int idx4 = t + sct * 256;            // 2048 float4s per tile
    int r = idx4 >> 4, k = (idx4 & 15) << 2;
    int pr = min(bi0 + r, M - 1);
    int ar = min(bj0 + r, N - 1);
    float4 v = *(const float4*)(P + (long)pr * 64 + k);
    Ps[k][r] = v.x; Ps[k + 1][r] = v.y; Ps[k + 2][r] = v.z; Ps[k + 3][r] = v.w;
    float4 w = *(const float4*)(A + (long)ar * 64 + k);
    As[k][r] = w.x; As[k + 1][r] = w.y; As[k + 2][r] = w.z; As[k + 3][r] = w.w;
  }
  __syncthreads();
  int tx = t & 15, ty = t >> 4;
  float acc[8][8];
  #pragma unroll
  for (int i = 0; i < 8; i++)
    #pragma unroll
    for (int j = 0; j < 8; j++) acc[i][j] = 0.0f;
  #pragma unroll 4
  for (int k = 0; k < 64; k++) {
    float a[8], b[8];
    #pragma unroll
    for (int i = 0; i < 8; i++) a[i] = Ps[k][ty * 8 + i];
    #pragma unroll
    for (int j = 0; j < 8; j++) b[j] = As[k][tx * 8 + j];
    #pragma unroll
    for (int i = 0; i < 8; i++)
      #pragma unroll
      for (int j = 0; j < 8; j++) acc[i][j] = fmaf(a[i], b[j], acc[i][j]);
  }
  #pragma unroll
  for (int i = 0; i < 8; i++) {
    int row = bi0 + ty * 8 + i;
    if (row >= M) continue;
    int colb = bj0 + tx * 8;
    if (colb + 7 < N) {
      float4 o0 = make_float4(acc[i][0] * scale, acc[i][1] * scale, acc[i][2] * scale, acc[i][3] * scale);
      float4 o1 = make_float4(acc[i][4] * scale, acc[i][5] * scale, acc[i][6] * scale, acc[i][7] * scale);
      *(float4*)(S + (long)row * N + colb) = o0;
      *(float4*)(S + (long)row * N + colb + 4) = o1;
    } else {
      for (int j = 0; j < 8 && colb + j < N; j++) S[(long)row * N + colb + j] = acc[i][j] * scale;
    }
  }
}

// one wave per row: online logsumexp over S row; adds -(diag - lse)*coeff to out[1]
__global__ void k_lse(const float* __restrict__ S, int N, float coeff, float* __restrict__ out) {
  constexpr float L2E = 1.44269504f;
  int row = blockIdx.x * 4 + (threadIdx.x >> 6);
  int lane = threadIdx.x & 63;
  const float* Sr = S + (long)row * N;
  float m = -1e30f, s = 0.0f;
  for (int w = 0; w < (N >> 8); w++) {
    float4 v = *(const float4*)(Sr + ((w << 6) + lane) * 4);
    float mx = fmaxf(fmaxf(v.x, v.y), fmaxf(v.z, v.w));
    if (mx > m) { s *= exp2f((m - mx) * L2E); m = mx; }
    s += exp2f((v.x - m) * L2E) + exp2f((v.y - m) * L2E) +
         exp2f((v.z - m) * L2E) + exp2f((v.w - m) * L2E);
  }
  #pragma unroll
  for (int o = 32; o >= 1; o >>= 1) {
    float m2 = __shfl_xor(m, o, 64), s2 = __shfl_xor(s, o, 64);
    float M = fmaxf(m, m2);
    s = s * exp2f((m - M) * L2E) + s2 * exp2f((m2 - M) * L2E);
    m = M;
  }
  if (lane == 0) {
    float lse = m + log2f(s) * 0.69314718f;
    unsafeAtomicAdd(&out[1], -(Sr[row] - lse) * coeff);
  }
}

extern "C" void kernel_launch(void* const* d_in, const int* in_sizes, int n_in,
                              void* d_out, int out_size, void* d_ws, size_t ws_size,
                              hipStream_t stream) {
  const int* users   = (const int*)d_in[0];
  const int* bundles = (const int*)d_in[1];
  const int* ui_u    = (const int*)d_in[2];
  const int* ui_i    = (const int*)d_in[3];
  const int* ub_u    = (const int*)d_in[4];
  const int* ub_b    = (const int*)d_in[5];
  const int* bi_b    = (const int*)d_in[6];
  const int* bi_i    = (const int*)d_in[7];
  const float* userF = (const float*)d_in[8];
  const float* bundF = (const float*)d_in[9];
  const float* itemF = (const float*)d_in[10];
  float* out = (float*)d_out;

  const int B    = in_sizes[0];
  const int E_ui = in_sizes[2];
  const int E_ub = in_sizes[4];
  const int E_bi = in_sizes[6];

  float* ws = (float*)d_ws;
  size_t off = 0;
  auto alloc = [&](size_t nfloat) -> float* {
    float* p = ws + off;
    off += (nfloat + 63) & ~(size_t)63;
    return p;
  };
  float* F1   = alloc((size_t)NILc * 64);
  float* F2   = alloc((size_t)NILc * 64);
  float* ACC  = alloc((size_t)NILc * 64);
  float* DINV = alloc(NILc);
  float* INV1 = alloc(NILc);
  float* INV2 = alloc(NILc);
  float* ILB  = alloc((size_t)NBUc * 64);
  float* ILu  = alloc((size_t)B * 64);
  float* BLu  = alloc((size_t)B * 64);
  float* ILb2 = alloc((size_t)B * 128);
  float* BLb2 = alloc((size_t)B * 128);
  float* PN1  = alloc((size_t)B * 64);
  float* AN1  = alloc((size_t)B * 64);
  float* PN2  = alloc((size_t)B * 64);
  float* AN2  = alloc((size_t)B * 64);
  // CSR buffers
  int* rp_ui  = (int*)alloc(NILc + 1);
  int* col_ui = (int*)alloc(2 * (size_t)E_ui);
  int* rp_ub  = (int*)alloc(NBLc + 1);
  int* col_ub = (int*)alloc(2 * (size_t)E_ub);
  int* rp_bi  = (int*)alloc(NBUc + 1);
  int* col_bi = (int*)alloc((size_t)E_bi);
  int* cntS   = (int*)alloc(NILc + 1);
  int* bCnt   = (int*)alloc(1024);
  int* bBase  = (int*)alloc(1024);
  int* bCur   = (int*)alloc(1024);
  int* bsum   = (int*)alloc(256);
  (void)ws_size; (void)n_in; (void)out_size;

  // S buffers alias F1/F2 (dead after BL k_acc)
  float* S1 = F1;   // needs B*B <= NILc*64 (4.2M <= 9.6M) OK
  float* S2 = F2;

  const int T = 256;
  auto nb = [&](long total) { return (int)((total + T - 1) / T); };

  auto scan_finish = [&](int* cnt, int* rp, int scan_n) {
    int nb1 = (scan_n + 1023) / 1024;
    k_scan_block<<<nb1, 256, 0, stream>>>(cnt, scan_n, rp, bsum);
    k_scan_bsum<<<1, 256, 0, stream>>>(bsum, nb1);
    k_scan_add<<<(scan_n + 255) / 256, 256, 0, stream>>>(rp, scan_n, bsum);
  };

  // ---- UI CSR: n=150000, shift=9 ----
  {
    const int SH = 9, NBK = (NILc + (1 << SH) - 1) >> SH;
    int2* binned = (int2*)F1;
    hipMemsetAsync(bCnt, 0, sizeof(int) * NBK, stream);
    k_bcount_sym<<<1024, T, 0, stream>>>(ui_u, ui_i, E_ui, NUc, SH, NBK, bCnt);
    k_scan512<<<1, 512, 0, stream>>>(bCnt, NBK, bBase, bCur);
    k_bin_sym<<<1024, T, 0, stream>>>(ui_u, ui_i, E_ui, NUc, SH, NBK, bCur, binned);
    hipMemsetAsync(cntS, 0, sizeof(int) * (NILc + 1), stream);
    k_rowhist<<<NBK, T, 0, stream>>>(binned, bBase, SH, NILc, cntS);
    scan_finish(cntS, rp_ui, NILc + 1);
    k_csrfill<<<NBK, T, 0, stream>>>(binned, bBase, SH, NILc, rp_ui, col_ui);
  }

  // ---- BI CSR: n=20000, shift=6 ----
  {
    const int SH = 6, NBK = (NBUc + (1 << SH) - 1) >> SH;
    int2* binned = (int2*)F2;
    hipMemsetAsync(bCnt, 0, sizeof(int) * NBK, stream);
    k_bcount_dir<<<1024, T, 0, stream>>>(bi_b, E_bi, SH, NBK, bCnt);
    k_scan512<<<1, 512, 0, stream>>>(bCnt, NBK, bBase, bCur);
    k_bin_dir<<<1024, T, 0, stream>>>(bi_b, bi_i, E_bi, SH, NBK, bCur, binned);
    hipMemsetAsync(cntS, 0, sizeof(int) * (NBUc + 1), stream);
    k_rowhist<<<NBK, T, 0, stream>>>(binned, bBase, SH, NBUc, cntS);
    scan_finish(cntS, rp_bi, NBUc + 1);
    k_csrfill<<<NBK, T, 0, stream>>>(binned, bBase, SH, NBUc, rp_bi, col_bi);
  }

  // ---------------- IL propagate (users+items) ----------------
  k_dinv_rp<<<nb(NILc), T, 0, stream>>>(rp_ui, DINV, NILc);
  k_spmm_csr<<<(NILc + 3) / 4, T, 0, stream>>>(rp_ui, col_ui, DINV, userF, itemF, NUc,
                                               F1, 0.5f, NILc);
  k_rownorm_inv<<<(NILc + 3) / 4, T, 0, stream>>>(F1, INV1, NILc);
  k_spmm_csr<<<(NILc + 3) / 4, T, 0, stream>>>(rp_ui, col_ui, DINV, F1, F1 + (size_t)NUc * 64,
                                               NUc, F2, 1.0f / 3.0f, NILc);
  k_rownorm_inv<<<(NILc + 3) / 4, T, 0, stream>>>(F2, INV2, NILc);
  k_acc<<<nb((long)NILc * 64), T, 0, stream>>>(userF, itemF, NUc, NILc, F1, INV1, F2, INV2, ACC);
  k_gather<<<nb((long)B * 64), T, 0, stream>>>(users, B, ACC, 0, ILu);

  k_agg_csr<<<(NBUc + 3) / 4, T, 0, stream>>>(rp_bi, col_bi, ACC + (size_t)NUc * 64, ILB, NBUc);
  k_gather<<<nb((long)2 * B * 64), T, 0, stream>>>(bundles, 2 * B, ILB, 0, ILb2);

  // ---- UB CSR: n=70000, shift=8 (F1 dead until BL spmm1) ----
  {
    const int SH = 8, NBK = (NBLc + (1 << SH) - 1) >> SH;
    int2* binned = (int2*)F1;
    hipMemsetAsync(bCnt, 0, sizeof(int) * NBK, stream);
    k_bcount_sym<<<1024, T, 0, stream>>>(ub_u, ub_b, E_ub, NUc, SH, NBK, bCnt);
    k_scan512<<<1, 512, 0, stream>>>(bCnt, NBK, bBase, bCur);
    k_bin_sym<<<1024, T, 0, stream>>>(ub_u, ub_b, E_ub, NUc, SH, NBK, bCur, binned);
    hipMemsetAsync(cntS, 0, sizeof(int) * (NBLc + 1), stream);
    k_rowhist<<<NBK, T, 0, stream>>>(binned, bBase, SH, NBLc, cntS);
    scan_finish(cntS, rp_ub, NBLc + 1);
    k_csrfill<<<NBK, T, 0, stream>>>(binned, bBase, SH, NBLc, rp_ub, col_ub);
  }

  // ---------------- BL propagate (users+bundles) ----------------
  k_dinv_rp<<<nb(NBLc), T, 0, stream>>>(rp_ub, DINV, NBLc);
  k_spmm_csr<<<(NBLc + 3) / 4, T, 0, stream>>>(rp_ub, col_ub, DINV, userF, bundF, NUc,
                                               F1, 0.5f, NBLc);
  k_rownorm_inv<<<(NBLc + 3) / 4, T, 0, stream>>>(F1, INV1, NBLc);
  k_spmm_csr<<<(NBLc + 3) / 4, T, 0, stream>>>(rp_ub, col_ub, DINV, F1, F1 + (size_t)NUc * 64,
                                               NUc, F2, 1.0f / 3.0f, NBLc);
  k_rownorm_inv<<<(NBLc + 3) / 4, T, 0, stream>>>(F2, INV2, NBLc);
  k_acc<<<nb((long)NBLc * 64), T, 0, stream>>>(userF, bundF, NUc, NBLc, F1, INV1, F2, INV2, ACC);
  k_gather<<<nb((long)B * 64), T, 0, stream>>>(users, B, ACC, 0, BLu);
  k_gather<<<nb((long)2 * B * 64), T, 0, stream>>>(bundles, 2 * B, ACC, NUc, BLb2);

  // ---------------- losses ----------------
  hipMemsetAsync(out, 0, 2 * sizeof(float), stream);
  k_bpr<<<(B + 3) / 4, T, 0, stream>>>(ILu, ILb2, BLu, BLb2, B, out);

  k_normalize<<<(B + 3) / 4, T, 0, stream>>>(ILu, 64, PN1, B);
  k_normalize<<<(B + 3) / 4, T, 0, stream>>>(BLu, 64, AN1, B);
  k_normalize<<<(B + 3) / 4, T, 0, stream>>>(ILb2, 128, PN2, B);
  k_normalize<<<(B + 3) / 4, T, 0, stream>>>(BLb2, 128, AN2, B);

  dim3 gg((B + 127) / 128, (B + 127) / 128);
  k_gemm_nt<<<gg, 256, 0, stream>>>(PN1, AN1, S1, B, B, 4.0f);   // 1/C_TEMP
  k_gemm_nt<<<gg, 256, 0, stream>>>(PN2, AN2, S2, B, B, 4.0f);
  k_lse<<<(B + 3) / 4, 256, 0, stream>>>(S1, B, 0.5f / (float)B, out);
  k_lse<<<(B + 3) / 4, 256, 0, stream>>>(S2, B, 0.5f / (float)B, out);
}

// Round 6
// 899.234 us; speedup vs baseline: 3.3700x; 1.1837x over previous
//
#include <hip/hip_runtime.h>
#include <hip/hip_bf16.h>
#include <math.h>

// CrossCBR: two L=2 graph propagations + bundle agg + BPR/InfoNCE losses.
// R6: SpMM gathers from bf16 mirrors with dinv pre-folded (X[r]=dinv[r]*f[r]),
// halving gather bytes; row-norm inverse + next-layer mirror fused into SpMM
// epilogue; dinv recomputed from rp (DINV buffer and 6 launches removed).
static constexpr int NUc  = 50000;
static constexpr int NBUc = 20000;
static constexpr int NIc  = 100000;
static constexpr int NILc = NUc + NIc;   // 150000 nodes in user-item graph
static constexpr int NBLc = NUc + NBUc;  // 70000 nodes in user-bundle graph

__device__ __forceinline__ float wredsum(float v) {
  #pragma unroll
  for (int m = 32; m >= 1; m >>= 1) v += __shfl_xor(v, m, 64);
  return v;
}

__device__ __forceinline__ float bf2f(unsigned short h) {
  return __uint_as_float(((unsigned int)h) << 16);
}
__device__ __forceinline__ unsigned short f2bf(float f) {  // RNE
  unsigned int u = __float_as_uint(f);
  return (unsigned short)((u + 0x7FFFu + ((u >> 16) & 1u)) >> 16);
}

// ---------------- bucketed CSR build ----------------
__global__ void k_bcount_sym(const int* __restrict__ eu, const int* __restrict__ ex,
                             int E, int off, int shift, int nbuck, int* __restrict__ bCnt) {
  __shared__ int hist[512];
  int chunk = (E + gridDim.x - 1) / gridDim.x;
  int c0 = blockIdx.x * chunk, c1 = min(E, c0 + chunk);
  for (int i = threadIdx.x; i < nbuck; i += blockDim.x) hist[i] = 0;
  __syncthreads();
  for (int e = c0 + threadIdx.x; e < c1; e += blockDim.x) {
    atomicAdd(&hist[eu[e] >> shift], 1);
    atomicAdd(&hist[(ex[e] + off) >> shift], 1);
  }
  __syncthreads();
  for (int i = threadIdx.x; i < nbuck; i += blockDim.x)
    if (hist[i]) atomicAdd(&bCnt[i], hist[i]);
}

__global__ void k_bcount_dir(const int* __restrict__ er, int E, int shift, int nbuck,
                             int* __restrict__ bCnt) {
  __shared__ int hist[512];
  int chunk = (E + gridDim.x - 1) / gridDim.x;
  int c0 = blockIdx.x * chunk, c1 = min(E, c0 + chunk);
  for (int i = threadIdx.x; i < nbuck; i += blockDim.x) hist[i] = 0;
  __syncthreads();
  for (int e = c0 + threadIdx.x; e < c1; e += blockDim.x)
    atomicAdd(&hist[er[e] >> shift], 1);
  __syncthreads();
  for (int i = threadIdx.x; i < nbuck; i += blockDim.x)
    if (hist[i]) atomicAdd(&bCnt[i], hist[i]);
}

__global__ void k_scan512(const int* __restrict__ data, int n, int* __restrict__ outBase,
                          int* __restrict__ outCur) {
  __shared__ int sh[512];
  int t = threadIdx.x;
  int v = (t < n) ? data[t] : 0;
  sh[t] = v;
  __syncthreads();
  for (int o = 1; o < 512; o <<= 1) {
    int x = (t >= o) ? sh[t - o] : 0;
    __syncthreads();
    sh[t] += x;
    __syncthreads();
  }
  int excl = sh[t] - v;
  if (t < n) { outBase[t] = excl; outCur[t] = excl; }
  if (t == n - 1) outBase[n] = sh[t];
}

__global__ void k_bin_sym(const int* __restrict__ eu, const int* __restrict__ ex,
                          int E, int off, int shift, int nbuck,
                          int* __restrict__ bCur, int2* __restrict__ binned) {
  __shared__ int hist[512];
  __shared__ int base[512];
  int chunk = (E + gridDim.x - 1) / gridDim.x;
  int c0 = blockIdx.x * chunk, c1 = min(E, c0 + chunk);
  for (int i = threadIdx.x; i < nbuck; i += blockDim.x) hist[i] = 0;
  __syncthreads();
  for (int e = c0 + threadIdx.x; e < c1; e += blockDim.x) {
    atomicAdd(&hist[eu[e] >> shift], 1);
    atomicAdd(&hist[(ex[e] + off) >> shift], 1);
  }
  __syncthreads();
  for (int i = threadIdx.x; i < nbuck; i += blockDim.x) {
    int h = hist[i];
    base[i] = h ? atomicAdd(&bCur[i], h) : 0;
    hist[i] = 0;
  }
  __syncthreads();
  for (int e = c0 + threadIdx.x; e < c1; e += blockDim.x) {
    int u = eu[e], x = ex[e] + off;
    int b1 = u >> shift;
    int p1 = base[b1] + atomicAdd(&hist[b1], 1);
    binned[p1] = make_int2(u, x);
    int b2 = x >> shift;
    int p2 = base[b2] + atomicAdd(&hist[b2], 1);
    binned[p2] = make_int2(x, u);
  }
}

__global__ void k_bin_dir(const int* __restrict__ er, const int* __restrict__ ec,
                          int E, int shift, int nbuck,
                          int* __restrict__ bCur, int2* __restrict__ binned) {
  __shared__ int hist[512];
  __shared__ int base[512];
  int chunk = (E + gridDim.x - 1) / gridDim.x;
  int c0 = blockIdx.x * chunk, c1 = min(E, c0 + chunk);
  for (int i = threadIdx.x; i < nbuck; i += blockDim.x) hist[i] = 0;
  __syncthreads();
  for (int e = c0 + threadIdx.x; e < c1; e += blockDim.x)
    atomicAdd(&hist[er[e] >> shift], 1);
  __syncthreads();
  for (int i = threadIdx.x; i < nbuck; i += blockDim.x) {
    int h = hist[i];
    base[i] = h ? atomicAdd(&bCur[i], h) : 0;
    hist[i] = 0;
  }
  __syncthreads();
  for (int e = c0 + threadIdx.x; e < c1; e += blockDim.x) {
    int r = er[e];
    int b1 = r >> shift;
    int p1 = base[b1] + atomicAdd(&hist[b1], 1);
    binned[p1] = make_int2(r, ec[e]);
  }
}

__global__ void k_rowhist(const int2* __restrict__ binned, const int* __restrict__ bBase,
                          int shift, int n, int* __restrict__ cnt) {
  __shared__ int hist[512];
  int b = blockIdx.x;
  int span = 1 << shift;
  int rowbase = b << shift;
  int s = bBase[b], e = bBase[b + 1];
  for (int i = threadIdx.x; i < span; i += blockDim.x) hist[i] = 0;
  __syncthreads();
  for (int i = s + threadIdx.x; i < e; i += blockDim.x)
    atomicAdd(&hist[binned[i].x - rowbase], 1);
  __syncthreads();
  for (int i = threadIdx.x; i < span; i += blockDim.x) {
    int row = rowbase + i;
    if (row < n) cnt[row] = hist[i];
  }
}

__global__ void k_csrfill(const int2* __restrict__ binned, const int* __restrict__ bBase,
                          int shift, int n, const int* __restrict__ rp, int* __restrict__ colv) {
  __shared__ int cur[512];
  int b = blockIdx.x;
  int span = 1 << shift;
  int rowbase = b << shift;
  int s = bBase[b], e = bBase[b + 1];
  for (int i = threadIdx.x; i < span; i += blockDim.x) {
    int row = rowbase + i;
    cur[i] = (row < n) ? rp[row] : 0;
  }
  __syncthreads();
  for (int i = s + threadIdx.x; i < e; i += blockDim.x) {
    int2 rc = binned[i];
    int pos = atomicAdd(&cur[rc.x - rowbase], 1);
    colv[pos] = rc.y;
  }
}

__global__ void k_scan_block(const int* __restrict__ in, int n, int* __restrict__ out,
                             int* __restrict__ bsum) {
  __shared__ int sh[256];
  int t = threadIdx.x;
  long base = (long)blockIdx.x * 1024 + (long)t * 4;
  int v0 = (base     < n) ? in[base]     : 0;
  int v1 = (base + 1 < n) ? in[base + 1] : 0;
  int v2 = (base + 2 < n) ? in[base + 2] : 0;
  int v3 = (base + 3 < n) ? in[base + 3] : 0;
  int tsum = v0 + v1 + v2 + v3;
  sh[t] = tsum;
  __syncthreads();
  for (int o = 1; o < 256; o <<= 1) {
    int x = (t >= o) ? sh[t - o] : 0;
    __syncthreads();
    sh[t] += x;
    __syncthreads();
  }
  int excl = sh[t] - tsum;
  if (t == 255) bsum[blockIdx.x] = sh[255];
  if (base     < n) out[base]     = excl;
  if (base + 1 < n) out[base + 1] = excl + v0;
  if (base + 2 < n) out[base + 2] = excl + v0 + v1;
  if (base + 3 < n) out[base + 3] = excl + v0 + v1 + v2;
}

__global__ void k_scan_bsum(int* __restrict__ bsum, int nb) {
  __shared__ int sh[256];
  int t = threadIdx.x;
  int v = (t < nb) ? bsum[t] : 0;
  sh[t] = v;
  __syncthreads();
  for (int o = 1; o < 256; o <<= 1) {
    int x = (t >= o) ? sh[t - o] : 0;
    __syncthreads();
    sh[t] += x;
    __syncthreads();
  }
  if (t < nb) bsum[t] = sh[t] - v;
}

__global__ void k_scan_add(int* __restrict__ out, int n, const int* __restrict__ bsum) {
  long i = (long)blockIdx.x * blockDim.x + threadIdx.x;
  if (i < n) out[i] += bsum[i >> 10];
}

// ---------------- bf16 mirrors ----------------
// X[r] = dinv[r] * f[r], dinv from rp degree; f split at off into fA/fB
__global__ void k_prescale(const int* __restrict__ rp,
                           const float* __restrict__ fA, const float* __restrict__ fB,
                           int off, int n, unsigned short* __restrict__ X) {
  long idx = (long)blockIdx.x * blockDim.x + threadIdx.x;
  if (idx >= (long)n * 64) return;
  int r = (int)(idx >> 6);
  float dinv = 1.0f / (sqrtf((float)(rp[r + 1] - rp[r])) + 1e-8f);
  float v = (r < off) ? fA[idx] : fB[idx - (long)off * 64];
  X[idx] = f2bf(v * dinv);
}

__global__ void k_tobf16(const float* __restrict__ src, unsigned short* __restrict__ dst, long n64) {
  long idx = (long)blockIdx.x * blockDim.x + threadIdx.x;
  if (idx < n64) dst[idx] = f2bf(src[idx]);
}

// ---------------- gather SpMM (bf16 source, dinv pre-folded) ----------------
// out[row] = dinv[row]*scale * sum_e X[col_e] ; optional bf16 mirror of
// dinv[row]*out (next layer's X) and optional 1/||out|| per row.
__global__ void k_spmm_b(const int* __restrict__ rp, const int* __restrict__ col,
                         const unsigned short* __restrict__ X,
                         float* __restrict__ out, unsigned short* __restrict__ outM,
                         float* __restrict__ outInv, float scale, int n) {
  int row = blockIdx.x * (blockDim.x >> 6) + (threadIdx.x >> 6);
  int lane = threadIdx.x & 63;
  if (row >= n) return;
  int s = rp[row], e = rp[row + 1];
  float dinv = 1.0f / (sqrtf((float)(e - s)) + 1e-8f);
  float acc = 0.0f;
  for (int chunk = s; chunk < e; chunk += 64) {
    int nc = min(64, e - chunk);
    int ci = 0;
    if (lane < nc) ci = col[chunk + lane];
    int j = 0;
    for (; j + 4 <= nc; j += 4) {
      int c0 = __shfl(ci, j, 64);
      int c1 = __shfl(ci, j + 1, 64);
      int c2 = __shfl(ci, j + 2, 64);
      int c3 = __shfl(ci, j + 3, 64);
      float x0 = bf2f(X[(long)c0 * 64 + lane]);
      float x1 = bf2f(X[(long)c1 * 64 + lane]);
      float x2 = bf2f(X[(long)c2 * 64 + lane]);
      float x3 = bf2f(X[(long)c3 * 64 + lane]);
      acc += (x0 + x1) + (x2 + x3);
    }
    for (; j < nc; j++) {
      int c0 = __shfl(ci, j, 64);
      acc += bf2f(X[(long)c0 * 64 + lane]);
    }
  }
  float res = acc * (dinv * scale);
  out[(long)row * 64 + lane] = res;
  if (outM) outM[(long)row * 64 + lane] = f2bf(res * dinv);
  if (outInv) {
    float ss = wredsum(res * res);
    if (lane == 0) outInv[row] = 1.0f / fmaxf(sqrtf(ss), 1e-12f);
  }
}

// bundle mean-agg from bf16 source
__global__ void k_agg_b(const int* __restrict__ rp, const int* __restrict__ col,
                        const unsigned short* __restrict__ src, float* __restrict__ out, int n) {
  int row = blockIdx.x * (blockDim.x >> 6) + (threadIdx.x >> 6);
  int lane = threadIdx.x & 63;
  if (row >= n) return;
  int s = rp[row], e = rp[row + 1];
  float acc = 0.0f;
  for (int chunk = s; chunk < e; chunk += 64) {
    int nc = min(64, e - chunk);
    int ci = 0;
    if (lane < nc) ci = col[chunk + lane];
    for (int j = 0; j < nc; j++) {
      int c0 = __shfl(ci, j, 64);
      acc += bf2f(src[(long)c0 * 64 + lane]);
    }
  }
  float w = 1.0f / ((float)(e - s) + 1e-8f);
  out[(long)row * 64 + lane] = acc * w;
}

// ---------------- misc ----------------
__global__ void k_acc(const float* __restrict__ fA, const float* __restrict__ fB, int off, int n,
                      const float* __restrict__ F1, const float* __restrict__ inv1,
                      const float* __restrict__ F2, const float* __restrict__ inv2,
                      float* __restrict__ acc) {
  long idx = (long)blockIdx.x * blockDim.x + threadIdx.x;
  if (idx >= (long)n * 64) return;
  int r = (int)(idx >> 6);
  float base = (r < off) ? fA[idx] : fB[idx - (long)off * 64];
  acc[idx] = base + F1[idx] * inv1[r] + F2[idx] * inv2[r];
}

__global__ void k_gather(const int* __restrict__ idx, int nrow, const float* __restrict__ src,
                         int srcOff, float* __restrict__ dst) {
  long i = (long)blockIdx.x * blockDim.x + threadIdx.x;
  if (i >= (long)nrow * 64) return;
  int r = (int)(i >> 6);
  int d = (int)(i & 63);
  dst[i] = src[(long)(idx[r] + srcOff) * 64 + d];
}

__global__ void k_normalize(const float* __restrict__ src, int stride, float* __restrict__ dst, int n) {
  int row = blockIdx.x * (blockDim.x >> 6) + (threadIdx.x >> 6);
  int lane = threadIdx.x & 63;
  if (row >= n) return;
  float v = src[(long)row * stride + lane];
  float s = wredsum(v * v);
  float inv = 1.0f / fmaxf(sqrtf(s), 1e-12f);
  dst[(long)row * 64 + lane] = v * inv;
}

__global__ void k_bpr(const float* __restrict__ ILu, const float* __restrict__ ILb2,
                      const float* __restrict__ BLu, const float* __restrict__ BLb2,
                      int B, float* __restrict__ out) {
  int row = blockIdx.x * (blockDim.x >> 6) + (threadIdx.x >> 6);
  int lane = threadIdx.x & 63;
  if (row >= B) return;
  float t = ILu[(long)row * 64 + lane] *
              (ILb2[(long)(2 * row) * 64 + lane] - ILb2[(long)(2 * row + 1) * 64 + lane]) +
            BLu[(long)row * 64 + lane] *
              (BLb2[(long)(2 * row) * 64 + lane] - BLb2[(long)(2 * row + 1) * 64 + lane]);
  float x = wredsum(t);
  if (lane == 0) {
    float ls = -(fmaxf(-x, 0.0f) + log1pf(expf(-fabsf(x))));
    unsafeAtomicAdd(&out[0], -ls / (float)B);
  }
}

// ---------------- InfoNCE: tiled GEMM + row LSE ----------------
__global__ void k_gemm_nt(const float* __restrict__ P, const float* __restrict__ A,
                          float* __restrict__ S, int M, int N, float scale) {
  __shared__ float Ps[64][129];
  __shared__ float As[64][129];
  int bi0 = blockIdx.y * 128, bj0 = blockIdx.x * 128;
  int t = threadIdx.x;  // 256
  #pragma unroll
  for (int sct = 0; sct < 8; sct++) {
    int idx4 = t + sct * 256;
    int r = idx4 >> 4, k = (idx4 & 15) << 2;
    int pr = min(bi0 + r, M - 1);
    int ar = min(bj0 + r, N - 1);
    float4 v = *(const float4*)(P + (long)pr * 64 + k);
    Ps[k][r] = v.x; Ps[k + 1][r] = v.y; Ps[k + 2][r] = v.z; Ps[k + 3][r] = v.w;
    float4 w = *(const float4*)(A + (long)ar * 64 + k);
    As[k][r] = w.x; As[k + 1][r] = w.y; As[k + 2][r] = w.z; As[k + 3][r] = w.w;
  }
  __syncthreads();
  int tx = t & 15, ty = t >> 4;
  float acc[8][8];
  #pragma unroll
  for (int i = 0; i < 8; i++)
    #pragma unroll
    for (int j = 0; j < 8; j++) acc[i][j] = 0.0f;
  #pragma unroll 4
  for (int k = 0; k < 64; k++) {
    float a[8], b[8];
    #pragma unroll
    for (int i = 0; i < 8; i++) a[i] = Ps[k][ty * 8 + i];
    #pragma unroll
    for (int j = 0; j < 8; j++) b[j] = As[k][tx * 8 + j];
    #pragma unroll
    for (int i = 0; i < 8; i++)
      #pragma unroll
      for (int j = 0; j < 8; j++) acc[i][j] = fmaf(a[i], b[j], acc[i][j]);
  }
  #pragma unroll
  for (int i = 0; i < 8; i++) {
    int row = bi0 + ty * 8 + i;
    if (row >= M) continue;
    int colb = bj0 + tx * 8;
    if (colb + 7 < N) {
      float4 o0 = make_float4(acc[i][0] * scale, acc[i][1] * scale, acc[i][2] * scale, acc[i][3] * scale);
      float4 o1 = make_float4(acc[i][4] * scale, acc[i][5] * scale, acc[i][6] * scale, acc[i][7] * scale);
      *(float4*)(S + (long)row * N + colb) = o0;
      *(float4*)(S + (long)row * N + colb + 4) = o1;
    } else {
      for (int j = 0; j < 8 && colb + j < N; j++) S[(long)row * N + colb + j] = acc[i][j] * scale;
    }
  }
}

__global__ void k_lse(const float* __restrict__ S, int N, float coeff, float* __restrict__ out) {
  constexpr float L2E = 1.44269504f;
  int row = blockIdx.x * 4 + (threadIdx.x >> 6);
  int lane = threadIdx.x & 63;
  const float* Sr = S + (long)row * N;
  float m = -1e30f, s = 0.0f;
  for (int w = 0; w < (N >> 8); w++) {
    float4 v = *(const float4*)(Sr + ((w << 6) + lane) * 4);
    float mx = fmaxf(fmaxf(v.x, v.y), fmaxf(v.z, v.w));
    if (mx > m) { s *= exp2f((m - mx) * L2E); m = mx; }
    s += exp2f((v.x - m) * L2E) + exp2f((v.y - m) * L2E) +
         exp2f((v.z - m) * L2E) + exp2f((v.w - m) * L2E);
  }
  #pragma unroll
  for (int o = 32; o >= 1; o >>= 1) {
    float m2 = __shfl_xor(m, o, 64), s2 = __shfl_xor(s, o, 64);
    float M = fmaxf(m, m2);
    s = s * exp2f((m - M) * L2E) + s2 * exp2f((m2 - M) * L2E);
    m = M;
  }
  if (lane == 0) {
    float lse = m + log2f(s) * 0.69314718f;
    unsafeAtomicAdd(&out[1], -(Sr[row] - lse) * coeff);
  }
}

extern "C" void kernel_launch(void* const* d_in, const int* in_sizes, int n_in,
                              void* d_out, int out_size, void* d_ws, size_t ws_size,
                              hipStream_t stream) {
  const int* users   = (const int*)d_in[0];
  const int* bundles = (const int*)d_in[1];
  const int* ui_u    = (const int*)d_in[2];
  const int* ui_i    = (const int*)d_in[3];
  const int* ub_u    = (const int*)d_in[4];
  const int* ub_b    = (const int*)d_in[5];
  const int* bi_b    = (const int*)d_in[6];
  const int* bi_i    = (const int*)d_in[7];
  const float* userF = (const float*)d_in[8];
  const float* bundF = (const float*)d_in[9];
  const float* itemF = (const float*)d_in[10];
  float* out = (float*)d_out;

  const int B    = in_sizes[0];
  const int E_ui = in_sizes[2];
  const int E_ub = in_sizes[4];
  const int E_bi = in_sizes[6];

  float* ws = (float*)d_ws;
  size_t off = 0;
  auto alloc = [&](size_t nfloat) -> float* {
    float* p = ws + off;
    off += (nfloat + 63) & ~(size_t)63;
    return p;
  };
  float* F1   = alloc((size_t)NILc * 64);
  float* F2   = alloc((size_t)NILc * 64);
  float* ACC  = alloc((size_t)NILc * 64);
  float* INV1 = alloc(NILc);
  float* INV2 = alloc(NILc);
  float* ILB  = alloc((size_t)NBUc * 64);
  float* ILu  = alloc((size_t)B * 64);
  float* BLu  = alloc((size_t)B * 64);
  float* ILb2 = alloc((size_t)B * 128);
  float* BLb2 = alloc((size_t)B * 128);
  float* PN1  = alloc((size_t)B * 64);
  float* AN1  = alloc((size_t)B * 64);
  float* PN2  = alloc((size_t)B * 64);
  float* AN2  = alloc((size_t)B * 64);
  unsigned short* XF = (unsigned short*)alloc((size_t)NILc * 32);  // bf16 NILc x 64
  // CSR buffers
  int* rp_ui  = (int*)alloc(NILc + 1);
  int* col_ui = (int*)alloc(2 * (size_t)E_ui);
  int* rp_ub  = (int*)alloc(NBLc + 1);
  int* col_ub = (int*)alloc(2 * (size_t)E_ub);
  int* rp_bi  = (int*)alloc(NBUc + 1);
  int* col_bi = (int*)alloc((size_t)E_bi);
  int* cntS   = (int*)alloc(NILc + 1);
  int* bCnt   = (int*)alloc(1024);
  int* bBase  = (int*)alloc(1024);
  int* bCur   = (int*)alloc(1024);
  int* bsum   = (int*)alloc(256);
  (void)ws_size; (void)n_in; (void)out_size;

  // aliases into dead phases:
  unsigned short* M1   = (unsigned short*)ACC;  // bf16 mirror of F1*dinv (19.2MB <= 38.4MB)
  unsigned short* MACC = (unsigned short*)F2;   // bf16 mirror of ACC items (12.8MB)
  float* S1 = F1;  // B*B fp32 similarity (16.8MB), F1/F2 dead after BL k_acc
  float* S2 = F2;

  const int T = 256;
  auto nb = [&](long total) { return (int)((total + T - 1) / T); };

  auto scan_finish = [&](int* cnt, int* rp, int scan_n) {
    int nb1 = (scan_n + 1023) / 1024;
    k_scan_block<<<nb1, 256, 0, stream>>>(cnt, scan_n, rp, bsum);
    k_scan_bsum<<<1, 256, 0, stream>>>(bsum, nb1);
    k_scan_add<<<(scan_n + 255) / 256, 256, 0, stream>>>(rp, scan_n, bsum);
  };

  // ---- UI CSR: n=150000, shift=9 (binned scratch in F1) ----
  {
    const int SH = 9, NBK = (NILc + (1 << SH) - 1) >> SH;
    int2* binned = (int2*)F1;
    hipMemsetAsync(bCnt, 0, sizeof(int) * NBK, stream);
    k_bcount_sym<<<1024, T, 0, stream>>>(ui_u, ui_i, E_ui, NUc, SH, NBK, bCnt);
    k_scan512<<<1, 512, 0, stream>>>(bCnt, NBK, bBase, bCur);
    k_bin_sym<<<1024, T, 0, stream>>>(ui_u, ui_i, E_ui, NUc, SH, NBK, bCur, binned);
    hipMemsetAsync(cntS, 0, sizeof(int) * (NILc + 1), stream);
    k_rowhist<<<NBK, T, 0, stream>>>(binned, bBase, SH, NILc, cntS);
    scan_finish(cntS, rp_ui, NILc + 1);
    k_csrfill<<<NBK, T, 0, stream>>>(binned, bBase, SH, NILc, rp_ui, col_ui);
  }

  // ---- BI CSR: n=20000, shift=6 (binned scratch in F2) ----
  {
    const int SH = 6, NBK = (NBUc + (1 << SH) - 1) >> SH;
    int2* binned = (int2*)F2;
    hipMemsetAsync(bCnt, 0, sizeof(int) * NBK, stream);
    k_bcount_dir<<<1024, T, 0, stream>>>(bi_b, E_bi, SH, NBK, bCnt);
    k_scan512<<<1, 512, 0, stream>>>(bCnt, NBK, bBase, bCur);
    k_bin_dir<<<1024, T, 0, stream>>>(bi_b, bi_i, E_bi, SH, NBK, bCur, binned);
    hipMemsetAsync(cntS, 0, sizeof(int) * (NBUc + 1), stream);
    k_rowhist<<<NBK, T, 0, stream>>>(binned, bBase, SH, NBUc, cntS);
    scan_finish(cntS, rp_bi, NBUc + 1);
    k_csrfill<<<NBK, T, 0, stream>>>(binned, bBase, SH, NBUc, rp_bi, col_bi);
  }

  // ---------------- IL propagate (users+items) ----------------
  k_prescale<<<nb((long)NILc * 64), T, 0, stream>>>(rp_ui, userF, itemF, NUc, NILc, XF);
  k_spmm_b<<<(NILc + 3) / 4, T, 0, stream>>>(rp_ui, col_ui, XF, F1, M1, INV1, 0.5f, NILc);
  k_spmm_b<<<(NILc + 3) / 4, T, 0, stream>>>(rp_ui, col_ui, M1, F2, nullptr, INV2,
                                             1.0f / 3.0f, NILc);
  k_acc<<<nb((long)NILc * 64), T, 0, stream>>>(userF, itemF, NUc, NILc, F1, INV1, F2, INV2, ACC);
  k_gather<<<nb((long)B * 64), T, 0, stream>>>(users, B, ACC, 0, ILu);

  // bundle aggregation from bf16 mirror of IL item embeddings (MACC in F2 region)
  k_tobf16<<<nb((long)NIc * 64), T, 0, stream>>>(ACC + (size_t)NUc * 64, MACC, (long)NIc * 64);
  k_agg_b<<<(NBUc + 3) / 4, T, 0, stream>>>(rp_bi, col_bi, MACC, ILB, NBUc);
  k_gather<<<nb((long)2 * B * 64), T, 0, stream>>>(bundles, 2 * B, ILB, 0, ILb2);

  // ---- UB CSR: n=70000, shift=8 (binned scratch in F1, dead after IL k_acc) ----
  {
    const int SH = 8, NBK = (NBLc + (1 << SH) - 1) >> SH;
    int2* binned = (int2*)F1;
    hipMemsetAsync(bCnt, 0, sizeof(int) * NBK, stream);
    k_bcount_sym<<<1024, T, 0, stream>>>(ub_u, ub_b, E_ub, NUc, SH, NBK, bCnt);
    k_scan512<<<1, 512, 0, stream>>>(bCnt, NBK, bBase, bCur);
    k_bin_sym<<<1024, T, 0, stream>>>(ub_u, ub_b, E_ub, NUc, SH, NBK, bCur, binned);
    hipMemsetAsync(cntS, 0, sizeof(int) * (NBLc + 1), stream);
    k_rowhist<<<NBK, T, 0, stream>>>(binned, bBase, SH, NBLc, cntS);
    scan_finish(cntS, rp_ub, NBLc + 1);
    k_csrfill<<<NBK, T, 0, stream>>>(binned, bBase, SH, NBLc, rp_ub, col_ub);
  }

  // ---------------- BL propagate (users+bundles) ----------------
  k_prescale<<<nb((long)NBLc * 64), T, 0, stream>>>(rp_ub, userF, bundF, NUc, NBLc, XF);
  k_spmm_b<<<(NBLc + 3) / 4, T, 0, stream>>>(rp_ub, col_ub, XF, F1, M1, INV1, 0.5f, NBLc);
  k_spmm_b<<<(NBLc + 3) / 4, T, 0, stream>>>(rp_ub, col_ub, M1, F2, nullptr, INV2,
                                             1.0f / 3.0f, NBLc);
  k_acc<<<nb((long)NBLc * 64), T, 0, stream>>>(userF, bundF, NUc, NBLc, F1, INV1, F2, INV2, ACC);
  k_gather<<<nb((long)B * 64), T, 0, stream>>>(users, B, ACC, 0, BLu);
  k_gather<<<nb((long)2 * B * 64), T, 0, stream>>>(bundles, 2 * B, ACC, NUc, BLb2);

  // ---------------- losses ----------------
  hipMemsetAsync(out, 0, 2 * sizeof(float), stream);
  k_bpr<<<(B + 3) / 4, T, 0, stream>>>(ILu, ILb2, BLu, BLb2, B, out);

  k_normalize<<<(B + 3) / 4, T, 0, stream>>>(ILu, 64, PN1, B);
  k_normalize<<<(B + 3) / 4, T, 0, stream>>>(BLu, 64, AN1, B);
  k_normalize<<<(B + 3) / 4, T, 0, stream>>>(ILb2, 128, PN2, B);
  k_normalize<<<(B + 3) / 4, T, 0, stream>>>(BLb2, 128, AN2, B);

  dim3 gg((B + 127) / 128, (B + 127) / 128);
  k_gemm_nt<<<gg, 256, 0, stream>>>(PN1, AN1, S1, B, B, 4.0f);   // 1/C_TEMP
  k_gemm_nt<<<gg, 256, 0, stream>>>(PN2, AN2, S2, B, B, 4.0f);
  k_lse<<<(B + 3) / 4, 256, 0, stream>>>(S1, B, 0.5f / (float)B, out);
  k_lse<<<(B + 3) / 4, 256, 0, stream>>>(S2, B, 0.5f / (float)B, out);
}

// Round 8
// 816.849 us; speedup vs baseline: 3.7099x; 1.1009x over previous
//
#include <hip/hip_runtime.h>
#include <hip/hip_bf16.h>
#include <math.h>

// CrossCBR: two L=2 graph propagations + bundle agg + BPR/InfoNCE losses.
// R7 (resubmit after infra failure): quarter-wave vectorized bf16 gather SpMM
// (uint2 per lane, 4 edges per load inst, ~3x fewer VALU inst/edge);
// conflict-free GEMM column mapping; normalize x4 fused; items-mirror fused
// into IL k_acc (aliases XF).
static constexpr int NUc  = 50000;
static constexpr int NBUc = 20000;
static constexpr int NIc  = 100000;
static constexpr int NILc = NUc + NIc;   // 150000 nodes in user-item graph
static constexpr int NBLc = NUc + NBUc;  // 70000 nodes in user-bundle graph

__device__ __forceinline__ float wredsum(float v) {
  #pragma unroll
  for (int m = 32; m >= 1; m >>= 1) v += __shfl_xor(v, m, 64);
  return v;
}

__device__ __forceinline__ float bf2f(unsigned short h) {
  return __uint_as_float(((unsigned int)h) << 16);
}
__device__ __forceinline__ unsigned short f2bf(float f) {  // RNE
  unsigned int u = __float_as_uint(f);
  return (unsigned short)((u + 0x7FFFu + ((u >> 16) & 1u)) >> 16);
}

// ---------------- bucketed CSR build ----------------
__global__ void k_bcount_sym(const int* __restrict__ eu, const int* __restrict__ ex,
                             int E, int off, int shift, int nbuck, int* __restrict__ bCnt) {
  __shared__ int hist[512];
  int chunk = (E + gridDim.x - 1) / gridDim.x;
  int c0 = blockIdx.x * chunk, c1 = min(E, c0 + chunk);
  for (int i = threadIdx.x; i < nbuck; i += blockDim.x) hist[i] = 0;
  __syncthreads();
  for (int e = c0 + threadIdx.x; e < c1; e += blockDim.x) {
    atomicAdd(&hist[eu[e] >> shift], 1);
    atomicAdd(&hist[(ex[e] + off) >> shift], 1);
  }
  __syncthreads();
  for (int i = threadIdx.x; i < nbuck; i += blockDim.x)
    if (hist[i]) atomicAdd(&bCnt[i], hist[i]);
}

__global__ void k_bcount_dir(const int* __restrict__ er, int E, int shift, int nbuck,
                             int* __restrict__ bCnt) {
  __shared__ int hist[512];
  int chunk = (E + gridDim.x - 1) / gridDim.x;
  int c0 = blockIdx.x * chunk, c1 = min(E, c0 + chunk);
  for (int i = threadIdx.x; i < nbuck; i += blockDim.x) hist[i] = 0;
  __syncthreads();
  for (int e = c0 + threadIdx.x; e < c1; e += blockDim.x)
    atomicAdd(&hist[er[e] >> shift], 1);
  __syncthreads();
  for (int i = threadIdx.x; i < nbuck; i += blockDim.x)
    if (hist[i]) atomicAdd(&bCnt[i], hist[i]);
}

__global__ void k_scan512(const int* __restrict__ data, int n, int* __restrict__ outBase,
                          int* __restrict__ outCur) {
  __shared__ int sh[512];
  int t = threadIdx.x;
  int v = (t < n) ? data[t] : 0;
  sh[t] = v;
  __syncthreads();
  for (int o = 1; o < 512; o <<= 1) {
    int x = (t >= o) ? sh[t - o] : 0;
    __syncthreads();
    sh[t] += x;
    __syncthreads();
  }
  int excl = sh[t] - v;
  if (t < n) { outBase[t] = excl; outCur[t] = excl; }
  if (t == n - 1) outBase[n] = sh[t];
}

__global__ void k_bin_sym(const int* __restrict__ eu, const int* __restrict__ ex,
                          int E, int off, int shift, int nbuck,
                          int* __restrict__ bCur, int2* __restrict__ binned) {
  __shared__ int hist[512];
  __shared__ int base[512];
  int chunk = (E + gridDim.x - 1) / gridDim.x;
  int c0 = blockIdx.x * chunk, c1 = min(E, c0 + chunk);
  for (int i = threadIdx.x; i < nbuck; i += blockDim.x) hist[i] = 0;
  __syncthreads();
  for (int e = c0 + threadIdx.x; e < c1; e += blockDim.x) {
    atomicAdd(&hist[eu[e] >> shift], 1);
    atomicAdd(&hist[(ex[e] + off) >> shift], 1);
  }
  __syncthreads();
  for (int i = threadIdx.x; i < nbuck; i += blockDim.x) {
    int h = hist[i];
    base[i] = h ? atomicAdd(&bCur[i], h) : 0;
    hist[i] = 0;
  }
  __syncthreads();
  for (int e = c0 + threadIdx.x; e < c1; e += blockDim.x) {
    int u = eu[e], x = ex[e] + off;
    int b1 = u >> shift;
    int p1 = base[b1] + atomicAdd(&hist[b1], 1);
    binned[p1] = make_int2(u, x);
    int b2 = x >> shift;
    int p2 = base[b2] + atomicAdd(&hist[b2], 1);
    binned[p2] = make_int2(x, u);
  }
}

__global__ void k_bin_dir(const int* __restrict__ er, const int* __restrict__ ec,
                          int E, int shift, int nbuck,
                          int* __restrict__ bCur, int2* __restrict__ binned) {
  __shared__ int hist[512];
  __shared__ int base[512];
  int chunk = (E + gridDim.x - 1) / gridDim.x;
  int c0 = blockIdx.x * chunk, c1 = min(E, c0 + chunk);
  for (int i = threadIdx.x; i < nbuck; i += blockDim.x) hist[i] = 0;
  __syncthreads();
  for (int e = c0 + threadIdx.x; e < c1; e += blockDim.x)
    atomicAdd(&hist[er[e] >> shift], 1);
  __syncthreads();
  for (int i = threadIdx.x; i < nbuck; i += blockDim.x) {
    int h = hist[i];
    base[i] = h ? atomicAdd(&bCur[i], h) : 0;
    hist[i] = 0;
  }
  __syncthreads();
  for (int e = c0 + threadIdx.x; e < c1; e += blockDim.x) {
    int r = er[e];
    int b1 = r >> shift;
    int p1 = base[b1] + atomicAdd(&hist[b1], 1);
    binned[p1] = make_int2(r, ec[e]);
  }
}

__global__ void k_rowhist(const int2* __restrict__ binned, const int* __restrict__ bBase,
                          int shift, int n, int* __restrict__ cnt) {
  __shared__ int hist[512];
  int b = blockIdx.x;
  int span = 1 << shift;
  int rowbase = b << shift;
  int s = bBase[b], e = bBase[b + 1];
  for (int i = threadIdx.x; i < span; i += blockDim.x) hist[i] = 0;
  __syncthreads();
  for (int i = s + threadIdx.x; i < e; i += blockDim.x)
    atomicAdd(&hist[binned[i].x - rowbase], 1);
  __syncthreads();
  for (int i = threadIdx.x; i < span; i += blockDim.x) {
    int row = rowbase + i;
    if (row < n) cnt[row] = hist[i];
  }
}

__global__ void k_csrfill(const int2* __restrict__ binned, const int* __restrict__ bBase,
                          int shift, int n, const int* __restrict__ rp, int* __restrict__ colv) {
  __shared__ int cur[512];
  int b = blockIdx.x;
  int span = 1 << shift;
  int rowbase = b << shift;
  int s = bBase[b], e = bBase[b + 1];
  for (int i = threadIdx.x; i < span; i += blockDim.x) {
    int row = rowbase + i;
    cur[i] = (row < n) ? rp[row] : 0;
  }
  __syncthreads();
  for (int i = s + threadIdx.x; i < e; i += blockDim.x) {
    int2 rc = binned[i];
    int pos = atomicAdd(&cur[rc.x - rowbase], 1);
    colv[pos] = rc.y;
  }
}

__global__ void k_scan_block(const int* __restrict__ in, int n, int* __restrict__ out,
                             int* __restrict__ bsum) {
  __shared__ int sh[256];
  int t = threadIdx.x;
  long base = (long)blockIdx.x * 1024 + (long)t * 4;
  int v0 = (base     < n) ? in[base]     : 0;
  int v1 = (base + 1 < n) ? in[base + 1] : 0;
  int v2 = (base + 2 < n) ? in[base + 2] : 0;
  int v3 = (base + 3 < n) ? in[base + 3] : 0;
  int tsum = v0 + v1 + v2 + v3;
  sh[t] = tsum;
  __syncthreads();
  for (int o = 1; o < 256; o <<= 1) {
    int x = (t >= o) ? sh[t - o] : 0;
    __syncthreads();
    sh[t] += x;
    __syncthreads();
  }
  int excl = sh[t] - tsum;
  if (t == 255) bsum[blockIdx.x] = sh[255];
  if (base     < n) out[base]     = excl;
  if (base + 1 < n) out[base + 1] = excl + v0;
  if (base + 2 < n) out[base + 2] = excl + v0 + v1;
  if (base + 3 < n) out[base + 3] = excl + v0 + v1 + v2;
}

__global__ void k_scan_bsum(int* __restrict__ bsum, int nb) {
  __shared__ int sh[256];
  int t = threadIdx.x;
  int v = (t < nb) ? bsum[t] : 0;
  sh[t] = v;
  __syncthreads();
  for (int o = 1; o < 256; o <<= 1) {
    int x = (t >= o) ? sh[t - o] : 0;
    __syncthreads();
    sh[t] += x;
    __syncthreads();
  }
  if (t < nb) bsum[t] = sh[t] - v;
}

__global__ void k_scan_add(int* __restrict__ out, int n, const int* __restrict__ bsum) {
  long i = (long)blockIdx.x * blockDim.x + threadIdx.x;
  if (i < n) out[i] += bsum[i >> 10];
}

// ---------------- bf16 mirrors ----------------
__global__ void k_prescale(const int* __restrict__ rp,
                           const float* __restrict__ fA, const float* __restrict__ fB,
                           int off, int n, unsigned short* __restrict__ X) {
  long idx = (long)blockIdx.x * blockDim.x + threadIdx.x;
  if (idx >= (long)n * 64) return;
  int r = (int)(idx >> 6);
  float dinv = 1.0f / (sqrtf((float)(rp[r + 1] - rp[r])) + 1e-8f);
  float v = (r < off) ? fA[idx] : fB[idx - (long)off * 64];
  X[idx] = f2bf(v * dinv);
}

// ---------------- vectorized gather SpMM (bf16 src, dinv pre-folded) ----------
// quarter q=lane>>4 handles edge 4*it+q; lane loads uint2 = 4 bf16 dims.
__global__ void k_spmm_v(const int* __restrict__ rp, const int* __restrict__ col,
                         const unsigned short* __restrict__ X,
                         float* __restrict__ out, unsigned short* __restrict__ outM,
                         float* __restrict__ outInv, float scale, int n) {
  int row = blockIdx.x * (blockDim.x >> 6) + (threadIdx.x >> 6);
  int lane = threadIdx.x & 63;
  if (row >= n) return;
  int q = lane >> 4, p = lane & 15;
  int s = rp[row], e = rp[row + 1];
  float dinv = 1.0f / (sqrtf((float)(e - s)) + 1e-8f);
  float a0 = 0.f, a1 = 0.f, a2 = 0.f, a3 = 0.f;
  for (int chunk = s; chunk < e; chunk += 64) {
    int nc = min(64, e - chunk);
    int ci = (lane < nc) ? col[chunk + lane] : 0;
    int nit = (nc + 3) >> 2;
    for (int it = 0; it < nit; it++) {
      int eidx = (it << 2) + q;
      int c = __shfl(ci, min(eidx, nc - 1), 64);
      uint2 v = ((const uint2*)(X + (long)c * 64))[p];
      if (eidx >= nc) { v.x = 0u; v.y = 0u; }
      a0 += __uint_as_float(v.x << 16);
      a1 += __uint_as_float(v.x & 0xFFFF0000u);
      a2 += __uint_as_float(v.y << 16);
      a3 += __uint_as_float(v.y & 0xFFFF0000u);
    }
  }
  // fold quarters
  a0 += __shfl_xor(a0, 32, 64); a1 += __shfl_xor(a1, 32, 64);
  a2 += __shfl_xor(a2, 32, 64); a3 += __shfl_xor(a3, 32, 64);
  a0 += __shfl_xor(a0, 16, 64); a1 += __shfl_xor(a1, 16, 64);
  a2 += __shfl_xor(a2, 16, 64); a3 += __shfl_xor(a3, 16, 64);
  float f = dinv * scale;
  float r0 = a0 * f, r1 = a1 * f, r2 = a2 * f, r3 = a3 * f;
  float ss = r0 * r0 + r1 * r1 + r2 * r2 + r3 * r3;
  ss += __shfl_xor(ss, 8, 64);
  ss += __shfl_xor(ss, 4, 64);
  ss += __shfl_xor(ss, 2, 64);
  ss += __shfl_xor(ss, 1, 64);
  if (q == 0) {
    *(float4*)(out + (long)row * 64 + p * 4) = make_float4(r0, r1, r2, r3);
    if (outM) {
      uint2 m;
      m.x = (unsigned int)f2bf(r0 * dinv) | ((unsigned int)f2bf(r1 * dinv) << 16);
      m.y = (unsigned int)f2bf(r2 * dinv) | ((unsigned int)f2bf(r3 * dinv) << 16);
      *(uint2*)(outM + (long)row * 64 + p * 4) = m;
    }
    if (outInv && p == 0) outInv[row] = 1.0f / fmaxf(sqrtf(ss), 1e-12f);
  }
}

// vectorized bundle mean-agg from plain bf16 source
__global__ void k_agg_v(const int* __restrict__ rp, const int* __restrict__ col,
                        const unsigned short* __restrict__ X, float* __restrict__ out, int n) {
  int row = blockIdx.x * (blockDim.x >> 6) + (threadIdx.x >> 6);
  int lane = threadIdx.x & 63;
  if (row >= n) return;
  int q = lane >> 4, p = lane & 15;
  int s = rp[row], e = rp[row + 1];
  float a0 = 0.f, a1 = 0.f, a2 = 0.f, a3 = 0.f;
  for (int chunk = s; chunk < e; chunk += 64) {
    int nc = min(64, e - chunk);
    int ci = (lane < nc) ? col[chunk + lane] : 0;
    int nit = (nc + 3) >> 2;
    for (int it = 0; it < nit; it++) {
      int eidx = (it << 2) + q;
      int c = __shfl(ci, min(eidx, nc - 1), 64);
      uint2 v = ((const uint2*)(X + (long)c * 64))[p];
      if (eidx >= nc) { v.x = 0u; v.y = 0u; }
      a0 += __uint_as_float(v.x << 16);
      a1 += __uint_as_float(v.x & 0xFFFF0000u);
      a2 += __uint_as_float(v.y << 16);
      a3 += __uint_as_float(v.y & 0xFFFF0000u);
    }
  }
  a0 += __shfl_xor(a0, 32, 64); a1 += __shfl_xor(a1, 32, 64);
  a2 += __shfl_xor(a2, 32, 64); a3 += __shfl_xor(a3, 32, 64);
  a0 += __shfl_xor(a0, 16, 64); a1 += __shfl_xor(a1, 16, 64);
  a2 += __shfl_xor(a2, 16, 64); a3 += __shfl_xor(a3, 16, 64);
  if (q == 0) {
    float w = 1.0f / ((float)(e - s) + 1e-8f);
    *(float4*)(out + (long)row * 64 + p * 4) = make_float4(a0 * w, a1 * w, a2 * w, a3 * w);
  }
}

// ---------------- misc ----------------
// acc = base + F1*inv1 + F2*inv2; optional bf16 mirror of rows >= mOff
__global__ void k_acc(const float* __restrict__ fA, const float* __restrict__ fB, int off, int n,
                      const float* __restrict__ F1, const float* __restrict__ inv1,
                      const float* __restrict__ F2, const float* __restrict__ inv2,
                      float* __restrict__ acc, unsigned short* __restrict__ mirror, int mOff) {
  long idx = (long)blockIdx.x * blockDim.x + threadIdx.x;
  if (idx >= (long)n * 64) return;
  int r = (int)(idx >> 6);
  float base = (r < off) ? fA[idx] : fB[idx - (long)off * 64];
  float res = base + F1[idx] * inv1[r] + F2[idx] * inv2[r];
  acc[idx] = res;
  if (mirror && r >= mOff) mirror[idx - (long)mOff * 64] = f2bf(res);
}

__global__ void k_gather(const int* __restrict__ idx, int nrow, const float* __restrict__ src,
                         int srcOff, float* __restrict__ dst) {
  long i = (long)blockIdx.x * blockDim.x + threadIdx.x;
  if (i >= (long)nrow * 64) return;
  int r = (int)(i >> 6);
  int d = (int)(i & 63);
  dst[i] = src[(long)(idx[r] + srcOff) * 64 + d];
}

// 4 normalizes in one launch: rows [0,B)->s0/d0 (stride 64), [B,2B)->s1/d1 (64),
// [2B,3B)->s2/d2 (128), [3B,4B)->s3/d3 (128)
__global__ void k_normalize4(const float* __restrict__ s0, const float* __restrict__ s1,
                             const float* __restrict__ s2, const float* __restrict__ s3,
                             float* __restrict__ d0, float* __restrict__ d1,
                             float* __restrict__ d2, float* __restrict__ d3, int B) {
  int row = blockIdx.x * (blockDim.x >> 6) + (threadIdx.x >> 6);
  int lane = threadIdx.x & 63;
  if (row >= 4 * B) return;
  int which = row / B, r = row - which * B;
  const float* src; float* dst; int stride;
  if (which == 0)      { src = s0; dst = d0; stride = 64; }
  else if (which == 1) { src = s1; dst = d1; stride = 64; }
  else if (which == 2) { src = s2; dst = d2; stride = 128; }
  else                 { src = s3; dst = d3; stride = 128; }
  float v = src[(long)r * stride + lane];
  float ss = wredsum(v * v);
  dst[(long)r * 64 + lane] = v * (1.0f / fmaxf(sqrtf(ss), 1e-12f));
}

__global__ void k_bpr(const float* __restrict__ ILu, const float* __restrict__ ILb2,
                      const float* __restrict__ BLu, const float* __restrict__ BLb2,
                      int B, float* __restrict__ out) {
  int row = blockIdx.x * (blockDim.x >> 6) + (threadIdx.x >> 6);
  int lane = threadIdx.x & 63;
  if (row >= B) return;
  float t = ILu[(long)row * 64 + lane] *
              (ILb2[(long)(2 * row) * 64 + lane] - ILb2[(long)(2 * row + 1) * 64 + lane]) +
            BLu[(long)row * 64 + lane] *
              (BLb2[(long)(2 * row) * 64 + lane] - BLb2[(long)(2 * row + 1) * 64 + lane]);
  float x = wredsum(t);
  if (lane == 0) {
    float ls = -(fmaxf(-x, 0.0f) + log1pf(expf(-fabsf(x))));
    unsafeAtomicAdd(&out[0], -ls / (float)B);
  }
}

// ---------------- InfoNCE: tiled GEMM + row LSE ----------------
// thread covers cols tx + 16*j (stride 16): conflict-free LDS reads.
__global__ void k_gemm_nt(const float* __restrict__ P, const float* __restrict__ A,
                          float* __restrict__ S, int M, int N, float scale) {
  __shared__ float Ps[64][129];
  __shared__ float As[64][129];
  int bi0 = blockIdx.y * 128, bj0 = blockIdx.x * 128;
  int t = threadIdx.x;  // 256
  #pragma unroll
  for (int sct = 0; sct < 8; sct++) {
    int idx4 = t + sct * 256;
    int r = idx4 >> 4, k = (idx4 & 15) << 2;
    int pr = min(bi0 + r, M - 1);
    int ar = min(bj0 + r, N - 1);
    float4 v = *(const float4*)(P + (long)pr * 64 + k);
    Ps[k][r] = v.x; Ps[k + 1][r] = v.y; Ps[k + 2][r] = v.z; Ps[k + 3][r] = v.w;
    float4 w = *(const float4*)(A + (long)ar * 64 + k);
    As[k][r] = w.x; As[k + 1][r] = w.y; As[k + 2][r] = w.z; As[k + 3][r] = w.w;
  }
  __syncthreads();
  int tx = t & 15, ty = t >> 4;
  float acc[8][8];
  #pragma unroll
  for (int i = 0; i < 8; i++)
    #pragma unroll
    for (int j = 0; j < 8; j++) acc[i][j] = 0.0f;
  #pragma unroll 4
  for (int k = 0; k < 64; k++) {
    float a[8], b[8];
    #pragma unroll
    for (int i = 0; i < 8; i++) a[i] = Ps[k][ty * 8 + i];
    #pragma unroll
    for (int j = 0; j < 8; j++) b[j] = As[k][tx + 16 * j];
    #pragma unroll
    for (int i = 0; i < 8; i++)
      #pragma unroll
      for (int j = 0; j < 8; j++) acc[i][j] = fmaf(a[i], b[j], acc[i][j]);
  }
  #pragma unroll
  for (int i = 0; i < 8; i++) {
    int row = bi0 + ty * 8 + i;
    if (row >= M) continue;
    #pragma unroll
    for (int j = 0; j < 8; j++) {
      int cc = bj0 + tx + 16 * j;
      if (cc < N) S[(long)row * N + cc] = acc[i][j] * scale;
    }
  }
}

__global__ void k_lse(const float* __restrict__ S, int N, float coeff, float* __restrict__ out) {
  constexpr float L2E = 1.44269504f;
  int row = blockIdx.x * 4 + (threadIdx.x >> 6);
  int lane = threadIdx.x & 63;
  const float* Sr = S + (long)row * N;
  float m = -1e30f, s = 0.0f;
  for (int w = 0; w < (N >> 8); w++) {
    float4 v = *(const float4*)(Sr + ((w << 6) + lane) * 4);
    float mx = fmaxf(fmaxf(v.x, v.y), fmaxf(v.z, v.w));
    if (mx > m) { s *= exp2f((m - mx) * L2E); m = mx; }
    s += exp2f((v.x - m) * L2E) + exp2f((v.y - m) * L2E) +
         exp2f((v.z - m) * L2E) + exp2f((v.w - m) * L2E);
  }
  #pragma unroll
  for (int o = 32; o >= 1; o >>= 1) {
    float m2 = __shfl_xor(m, o, 64), s2 = __shfl_xor(s, o, 64);
    float M = fmaxf(m, m2);
    s = s * exp2f((m - M) * L2E) + s2 * exp2f((m2 - M) * L2E);
    m = M;
  }
  if (lane == 0) {
    float lse = m + log2f(s) * 0.69314718f;
    unsafeAtomicAdd(&out[1], -(Sr[row] - lse) * coeff);
  }
}

extern "C" void kernel_launch(void* const* d_in, const int* in_sizes, int n_in,
                              void* d_out, int out_size, void* d_ws, size_t ws_size,
                              hipStream_t stream) {
  const int* users   = (const int*)d_in[0];
  const int* bundles = (const int*)d_in[1];
  const int* ui_u    = (const int*)d_in[2];
  const int* ui_i    = (const int*)d_in[3];
  const int* ub_u    = (const int*)d_in[4];
  const int* ub_b    = (const int*)d_in[5];
  const int* bi_b    = (const int*)d_in[6];
  const int* bi_i    = (const int*)d_in[7];
  const float* userF = (const float*)d_in[8];
  const float* bundF = (const float*)d_in[9];
  const float* itemF = (const float*)d_in[10];
  float* out = (float*)d_out;

  const int B    = in_sizes[0];
  const int E_ui = in_sizes[2];
  const int E_ub = in_sizes[4];
  const int E_bi = in_sizes[6];

  float* ws = (float*)d_ws;
  size_t off = 0;
  auto alloc = [&](size_t nfloat) -> float* {
    float* p = ws + off;
    off += (nfloat + 63) & ~(size_t)63;
    return p;
  };
  float* F1   = alloc((size_t)NILc * 64);
  float* F2   = alloc((size_t)NILc * 64);
  float* ACC  = alloc((size_t)NILc * 64);
  float* INV1 = alloc(NILc);
  float* INV2 = alloc(NILc);
  float* ILB  = alloc((size_t)NBUc * 64);
  float* ILu  = alloc((size_t)B * 64);
  float* BLu  = alloc((size_t)B * 64);
  float* ILb2 = alloc((size_t)B * 128);
  float* BLb2 = alloc((size_t)B * 128);
  float* PN1  = alloc((size_t)B * 64);
  float* AN1  = alloc((size_t)B * 64);
  float* PN2  = alloc((size_t)B * 64);
  float* AN2  = alloc((size_t)B * 64);
  unsigned short* XF = (unsigned short*)alloc((size_t)NILc * 32);  // bf16 NILc x 64
  // CSR buffers
  int* rp_ui  = (int*)alloc(NILc + 1);
  int* col_ui = (int*)alloc(2 * (size_t)E_ui);
  int* rp_ub  = (int*)alloc(NBLc + 1);
  int* col_ub = (int*)alloc(2 * (size_t)E_ub);
  int* rp_bi  = (int*)alloc(NBUc + 1);
  int* col_bi = (int*)alloc((size_t)E_bi);
  int* cntS   = (int*)alloc(NILc + 1);
  int* bCnt   = (int*)alloc(1024);
  int* bBase  = (int*)alloc(1024);
  int* bCur   = (int*)alloc(1024);
  int* bsum   = (int*)alloc(256);
  (void)ws_size; (void)n_in; (void)out_size;

  // aliases into dead phases:
  unsigned short* M1   = (unsigned short*)ACC;  // bf16 mirror of F1*dinv
  unsigned short* MACC = XF;                    // bf16 mirror of ACC items: XF dead
                                                // after IL spmm1; rewritten by BL prescale
  float* S1 = F1;  // B*B fp32 similarity, F1/F2 dead after BL k_acc
  float* S2 = F2;

  const int T = 256;
  auto nb = [&](long total) { return (int)((total + T - 1) / T); };

  auto scan_finish = [&](int* cnt, int* rp, int scan_n) {
    int nb1 = (scan_n + 1023) / 1024;
    k_scan_block<<<nb1, 256, 0, stream>>>(cnt, scan_n, rp, bsum);
    k_scan_bsum<<<1, 256, 0, stream>>>(bsum, nb1);
    k_scan_add<<<(scan_n + 255) / 256, 256, 0, stream>>>(rp, scan_n, bsum);
  };

  // ---- UI CSR: n=150000, shift=9 (binned scratch in F1) ----
  {
    const int SH = 9, NBK = (NILc + (1 << SH) - 1) >> SH;
    int2* binned = (int2*)F1;
    hipMemsetAsync(bCnt, 0, sizeof(int) * NBK, stream);
    k_bcount_sym<<<1024, T, 0, stream>>>(ui_u, ui_i, E_ui, NUc, SH, NBK, bCnt);
    k_scan512<<<1, 512, 0, stream>>>(bCnt, NBK, bBase, bCur);
    k_bin_sym<<<1024, T, 0, stream>>>(ui_u, ui_i, E_ui, NUc, SH, NBK, bCur, binned);
    hipMemsetAsync(cntS, 0, sizeof(int) * (NILc + 1), stream);
    k_rowhist<<<NBK, T, 0, stream>>>(binned, bBase, SH, NILc, cntS);
    scan_finish(cntS, rp_ui, NILc + 1);
    k_csrfill<<<NBK, T, 0, stream>>>(binned, bBase, SH, NILc, rp_ui, col_ui);
  }

  // ---- BI CSR: n=20000, shift=6 (binned scratch in F2) ----
  {
    const int SH = 6, NBK = (NBUc + (1 << SH) - 1) >> SH;
    int2* binned = (int2*)F2;
    hipMemsetAsync(bCnt, 0, sizeof(int) * NBK, stream);
    k_bcount_dir<<<1024, T, 0, stream>>>(bi_b, E_bi, SH, NBK, bCnt);
    k_scan512<<<1, 512, 0, stream>>>(bCnt, NBK, bBase, bCur);
    k_bin_dir<<<1024, T, 0, stream>>>(bi_b, bi_i, E_bi, SH, NBK, bCur, binned);
    hipMemsetAsync(cntS, 0, sizeof(int) * (NBUc + 1), stream);
    k_rowhist<<<NBK, T, 0, stream>>>(binned, bBase, SH, NBUc, cntS);
    scan_finish(cntS, rp_bi, NBUc + 1);
    k_csrfill<<<NBK, T, 0, stream>>>(binned, bBase, SH, NBUc, rp_bi, col_bi);
  }

  // ---------------- IL propagate (users+items) ----------------
  k_prescale<<<nb((long)NILc * 64), T, 0, stream>>>(rp_ui, userF, itemF, NUc, NILc, XF);
  k_spmm_v<<<(NILc + 3) / 4, T, 0, stream>>>(rp_ui, col_ui, XF, F1, M1, INV1, 0.5f, NILc);
  k_spmm_v<<<(NILc + 3) / 4, T, 0, stream>>>(rp_ui, col_ui, M1, F2, nullptr, INV2,
                                             1.0f / 3.0f, NILc);
  // k_acc writes ACC and bf16 item-mirror into MACC(=XF, dead here)
  k_acc<<<nb((long)NILc * 64), T, 0, stream>>>(userF, itemF, NUc, NILc, F1, INV1, F2, INV2,
                                               ACC, MACC, NUc);
  k_gather<<<nb((long)B * 64), T, 0, stream>>>(users, B, ACC, 0, ILu);

  k_agg_v<<<(NBUc + 3) / 4, T, 0, stream>>>(rp_bi, col_bi, MACC, ILB, NBUc);
  k_gather<<<nb((long)2 * B * 64), T, 0, stream>>>(bundles, 2 * B, ILB, 0, ILb2);

  // ---- UB CSR: n=70000, shift=8 (binned scratch in F1, dead after IL k_acc) ----
  {
    const int SH = 8, NBK = (NBLc + (1 << SH) - 1) >> SH;
    int2* binned = (int2*)F1;
    hipMemsetAsync(bCnt, 0, sizeof(int) * NBK, stream);
    k_bcount_sym<<<1024, T, 0, stream>>>(ub_u, ub_b, E_ub, NUc, SH, NBK, bCnt);
    k_scan512<<<1, 512, 0, stream>>>(bCnt, NBK, bBase, bCur);
    k_bin_sym<<<1024, T, 0, stream>>>(ub_u, ub_b, E_ub, NUc, SH, NBK, bCur, binned);
    hipMemsetAsync(cntS, 0, sizeof(int) * (NBLc + 1), stream);
    k_rowhist<<<NBK, T, 0, stream>>>(binned, bBase, SH, NBLc, cntS);
    scan_finish(cntS, rp_ub, NBLc + 1);
    k_csrfill<<<NBK, T, 0, stream>>>(binned, bBase, SH, NBLc, rp_ub, col_ub);
  }

  // ---------------- BL propagate (users+bundles) ----------------
  k_prescale<<<nb((long)NBLc * 64), T, 0, stream>>>(rp_ub, userF, bundF, NUc, NBLc, XF);
  k_spmm_v<<<(NBLc + 3) / 4, T, 0, stream>>>(rp_ub, col_ub, XF, F1, M1, INV1, 0.5f, NBLc);
  k_spmm_v<<<(NBLc + 3) / 4, T, 0, stream>>>(rp_ub, col_ub, M1, F2, nullptr, INV2,
                                             1.0f / 3.0f, NBLc);
  k_acc<<<nb((long)NBLc * 64), T, 0, stream>>>(userF, bundF, NUc, NBLc, F1, INV1, F2, INV2,
                                               ACC, nullptr, 0);
  k_gather<<<nb((long)B * 64), T, 0, stream>>>(users, B, ACC, 0, BLu);
  k_gather<<<nb((long)2 * B * 64), T, 0, stream>>>(bundles, 2 * B, ACC, NUc, BLb2);

  // ---------------- losses ----------------
  hipMemsetAsync(out, 0, 2 * sizeof(float), stream);
  k_bpr<<<(B + 3) / 4, T, 0, stream>>>(ILu, ILb2, BLu, BLb2, B, out);

  k_normalize4<<<(4 * B + 3) / 4, T, 0, stream>>>(ILu, BLu, ILb2, BLb2,
                                                  PN1, AN1, PN2, AN2, B);

  dim3 gg((B + 127) / 128, (B + 127) / 128);
  k_gemm_nt<<<gg, 256, 0, stream>>>(PN1, AN1, S1, B, B, 4.0f);   // 1/C_TEMP
  k_gemm_nt<<<gg, 256, 0, stream>>>(PN2, AN2, S2, B, B, 4.0f);
  k_lse<<<(B + 3) / 4, 256, 0, stream>>>(S1, B, 0.5f / (float)B, out);
  k_lse<<<(B + 3) / 4, 256, 0, stream>>>(S2, B, 0.5f / (float)B, out);
}